// Round 2
// baseline (644.915 us; speedup 1.0000x reference)
//
#include <hip/hip_runtime.h>
#include <hip/hip_bf16.h>
#include <math.h>

#define B_ 4
#define R_ 256
#define P_ 64
#define DP_ 384
#define DR_ 512
#define N_ 48
#define RK_ 24
#define MROWS (B_*R_*P_)   /* 65536 */
#define REGS  (B_*R_)      /* 1024  */

typedef unsigned short ushort_t;
typedef __attribute__((ext_vector_type(8))) short bf16x8;
typedef __attribute__((ext_vector_type(4))) float f32x4;

__device__ __forceinline__ float us2f(unsigned short u){
  union { unsigned int i; float f; } x; x.i = ((unsigned int)u) << 16; return x.f;
}
__device__ __forceinline__ unsigned short f2us(float f){
  __hip_bfloat16 h = __float2bfloat16(f);
  return *reinterpret_cast<unsigned short*>(&h);
}
__device__ __forceinline__ float gelu_f(float x){
  return 0.5f * x * (1.0f + erff(x * 0.70710678118654752f));
}
__device__ __forceinline__ float wred_sum(float v){
#pragma unroll
  for (int m = 1; m < 64; m <<= 1) v += __shfl_xor(v, m, 64);
  return v;
}
// block-wide sum; s must have >= 9 floats of LDS scratch
__device__ __forceinline__ float block_sum(float v, float* s){
  float w = wred_sum(v);
  int lane = threadIdx.x & 63, wid = threadIdx.x >> 6, nw = blockDim.x >> 6;
  if (lane == 0) s[wid] = w;
  __syncthreads();
  if (threadIdx.x == 0){ float t = 0.f; for (int i = 0; i < nw; i++) t += s[i]; s[8] = t; }
  __syncthreads();
  float r = s[8];
  __syncthreads();
  return r;
}

// ---------------- C0: weight prep (W1pT bf16, s1, b1p) + zero loss accum ----
__global__ void k_prep(const float* __restrict__ gw1, const float* __restrict__ glnw,
                       const float* __restrict__ glnb, const float* __restrict__ gb1,
                       ushort_t* __restrict__ W1pT, float* __restrict__ s1,
                       float* __restrict__ b1p, float* __restrict__ accum){
  int n = blockIdx.x * 64 + threadIdx.x;   // 0..511
  if (blockIdx.x == 0 && threadIdx.x < 4) accum[threadIdx.x] = 0.f;
  float s = 0.f, sb = 0.f;
  for (int k = 0; k < DP_; ++k){
    float w1 = gw1[k * DR_ + n];
    float v = glnw[k] * w1;
    unsigned short vr = f2us(v);
    s  += us2f(vr);              // consistent with what the bf16 GEMM sees
    sb += glnb[k] * w1;
    W1pT[n * DP_ + k] = vr;
  }
  s1[n] = s;
  b1p[n] = gb1[n] + sb;
}

// ---------------- C1: lpW[p][n] = local_pos[p] . W1p[:,n] ------------------
__global__ void k_lpw(const float* __restrict__ lp, const ushort_t* __restrict__ W1pT,
                      float* __restrict__ lpW){
  __shared__ float lps[DP_];
  int p = blockIdx.x, n = threadIdx.x;
  if (n < DP_) lps[n] = lp[p * DP_ + n];
  __syncthreads();
  float a = 0.f;
  for (int k = 0; k < DP_; ++k) a += lps[k] * us2f(W1pT[n * DP_ + k]);
  lpW[p * DR_ + n] = a;
}

// ---------------- S0: per patch-row LN stats of x = pt + lp ----------------
__global__ void k_stats(const float* __restrict__ pt, const float* __restrict__ lp,
                        float* __restrict__ mu, float* __restrict__ rsg){
  int row  = blockIdx.x * 4 + (threadIdx.x >> 6);
  int lane = threadIdx.x & 63;
  int p = row & (P_ - 1);
  const float* xr = pt + (size_t)row * DP_ + lane * 6;
  const float* lr = lp + p * DP_ + lane * 6;
  float s = 0.f, ss = 0.f;
#pragma unroll
  for (int i = 0; i < 6; ++i){
    float v = xr[i] + lr[i];
    s += v; ss += v * v;
  }
  s = wred_sum(s); ss = wred_sum(ss);
  if (lane == 0){
    float m = s * (1.f / DP_);
    float var = ss * (1.f / DP_) - m * m;
    mu[row]  = m;
    rsg[row] = rsqrtf(var + 1e-5f);
  }
}

// ---------------- P2: gate GEMM (pt @ W1p) + folded LN + gelu + logit ------
// BM=64 (one region), BN=512 (full), BK=64; 512 threads = 8 waves
__global__ __launch_bounds__(512, 2) void k_gate_gemm(
    const float* __restrict__ A,       // pt (65536 x 384) f32
    const ushort_t* __restrict__ BT,   // W1pT (512 x 384) bf16
    const float* __restrict__ mu, const float* __restrict__ rsg,
    const float* __restrict__ s1, const float* __restrict__ b1p,
    const float* __restrict__ lpW,     // (64 x 512) f32
    const float* __restrict__ w2, const float* __restrict__ b2g,
    float* __restrict__ logits){
  __shared__ ushort_t As[64 * 64];
  __shared__ ushort_t Bs[512 * 64];
  __shared__ float logit_lds[64];
  int tid = threadIdx.x;
  int lane = tid & 63, w = tid >> 6;
  int t = lane & 15, g = lane >> 4;
  long r0 = (long)blockIdx.x * 64;
  if (tid < 64) logit_lds[tid] = 0.f;

  f32x4 acc[4][4];
#pragma unroll
  for (int m = 0; m < 4; ++m)
#pragma unroll
    for (int n = 0; n < 4; ++n) acc[m][n] = (f32x4){0.f, 0.f, 0.f, 0.f};

  int arow = tid >> 3, acol = (tid & 7) * 8;
  const float* ag = A + (r0 + arow) * DP_ + acol;

  for (int kt = 0; kt < 6; ++kt){
    float4 a0 = *(const float4*)(ag + kt * 64);
    float4 a1 = *(const float4*)(ag + kt * 64 + 4);
    bf16x8 ar;
    ar[0] = (short)f2us(a0.x); ar[1] = (short)f2us(a0.y);
    ar[2] = (short)f2us(a0.z); ar[3] = (short)f2us(a0.w);
    ar[4] = (short)f2us(a1.x); ar[5] = (short)f2us(a1.y);
    ar[6] = (short)f2us(a1.z); ar[7] = (short)f2us(a1.w);
    bf16x8 br[8];
#pragma unroll
    for (int j = 0; j < 8; ++j){
      int nb = j * 64 + (tid >> 3);
      br[j] = *(const bf16x8*)(BT + nb * DP_ + kt * 64 + acol);
    }
    __syncthreads();
    *(bf16x8*)(As + tid * 8) = ar;
#pragma unroll
    for (int j = 0; j < 8; ++j) *(bf16x8*)(Bs + (j * 512 + tid) * 8) = br[j];
    __syncthreads();
#pragma unroll
    for (int kk = 0; kk < 2; ++kk){
      bf16x8 af[4], bfr[4];
      int ko = kk * 32 + g * 8;
#pragma unroll
      for (int m = 0; m < 4; ++m) af[m]  = *(const bf16x8*)(As + (m * 16 + t) * 64 + ko);
#pragma unroll
      for (int n = 0; n < 4; ++n) bfr[n] = *(const bf16x8*)(Bs + (w * 64 + n * 16 + t) * 64 + ko);
#pragma unroll
      for (int m = 0; m < 4; ++m)
#pragma unroll
        for (int n = 0; n < 4; ++n)
          acc[m][n] = __builtin_amdgcn_mfma_f32_16x16x32_bf16(af[m], bfr[n], acc[m][n], 0, 0, 0);
    }
  }
  __syncthreads();

  // epilogue: folded LN + gelu + reduce against gate_w2
  float w2c[4], s1c[4], b1c[4];
#pragma unroll
  for (int n = 0; n < 4; ++n){
    int c = w * 64 + n * 16 + t;
    w2c[n] = w2[c]; s1c[n] = s1[c]; b1c[n] = b1p[c];
  }
#pragma unroll
  for (int m = 0; m < 4; ++m){
#pragma unroll
    for (int j = 0; j < 4; ++j){
      int rl = m * 16 + g * 4 + j;           // local row == p
      long rg = r0 + rl;
      float mur = mu[rg], rs = rsg[rg];
      float part = 0.f;
#pragma unroll
      for (int n = 0; n < 4; ++n){
        int c = w * 64 + n * 16 + t;
        float gp = rs * (acc[m][n][j] + lpW[rl * DR_ + c]) - mur * rs * s1c[n] + b1c[n];
        part += gelu_f(gp) * w2c[n];
      }
#pragma unroll
      for (int msk = 1; msk < 16; msk <<= 1) part += __shfl_xor(part, msk, 64);
      if (t == 0) atomicAdd(&logit_lds[rl], part);
    }
  }
  __syncthreads();
  if (tid < 64) logits[r0 + tid] = logit_lds[tid] + b2g[0];
}

// ---------------- P3: masked softmax over P + attention pooling ------------
__global__ void k_pool(const float* __restrict__ pt, const float* __restrict__ lp,
                       const float* __restrict__ logits, const int* __restrict__ pmask,
                       float* __restrict__ pooled){
  __shared__ float attn[64];
  int reg = blockIdx.x, tid = threadIdx.x;
  long base = (long)reg * 64;
  if (tid < 64){
    int mk = pmask[base + tid];
    float lv = logits[base + tid];
    float lm = mk ? lv : -3.4e38f;
    float M = lm;
#pragma unroll
    for (int m2 = 1; m2 < 64; m2 <<= 1) M = fmaxf(M, __shfl_xor(M, m2, 64));
    float e = mk ? expf(lv - M) : 0.f;
    float S = e;
#pragma unroll
    for (int m2 = 1; m2 < 64; m2 <<= 1) S += __shfl_xor(S, m2, 64);
    float a = (S > 0.f) ? e / S : 0.f;
    float S2 = a;
#pragma unroll
    for (int m2 = 1; m2 < 64; m2 <<= 1) S2 += __shfl_xor(S2, m2, 64);
    attn[tid] = a / fmaxf(S2, 1e-6f);
  }
  __syncthreads();
  float acc0 = 0.f, acc1 = 0.f;
  int d0 = tid, d1 = tid + 256;
  for (int p = 0; p < 64; ++p){
    float ap = attn[p];
    const float* xr = pt + (base + p) * DP_;
    const float* lr = lp + p * DP_;
    acc0 += ap * (xr[d0] + lr[d0]);
    if (tid < DP_ - 256) acc1 += ap * (xr[d1] + lr[d1]);
  }
  pooled[(long)reg * DP_ + d0] = acc0;
  if (tid < DP_ - 256) pooled[(long)reg * DP_ + d1] = acc1;
}

// ---------------- R1: region MLP (LN -> gelu W1 -> W2 -> LN -> l2norm) -----
__global__ void k_region_mlp(const float* __restrict__ pooled,
                             const float* __restrict__ ln1w, const float* __restrict__ ln1b,
                             const float* __restrict__ pw1, const float* __restrict__ pb1,
                             const float* __restrict__ pw2, const float* __restrict__ pb2,
                             const float* __restrict__ ln2w, const float* __restrict__ ln2b,
                             float* __restrict__ region){
  __shared__ float xr[DP_];
  __shared__ float p1[DR_];
  __shared__ float red[9];
  int row = blockIdx.x, tid = threadIdx.x;
  if (tid < DP_) xr[tid] = pooled[(long)row * DP_ + tid];
  __syncthreads();
  float v = (tid < DP_) ? xr[tid] : 0.f;
  float mean = block_sum(v, red) / DP_;
  float dv = (tid < DP_) ? (v - mean) : 0.f;
  float var = block_sum(dv * dv, red) / DP_;
  float rs = rsqrtf(var + 1e-5f);
  __syncthreads();
  if (tid < DP_) xr[tid] = dv * rs * ln1w[tid] + ln1b[tid];
  __syncthreads();
  float a = pb1[tid];
  for (int k = 0; k < DP_; ++k) a += xr[k] * pw1[k * DR_ + tid];
  p1[tid] = gelu_f(a);
  __syncthreads();
  float q = pb2[tid];
  for (int k = 0; k < DR_; ++k) q += p1[k] * pw2[k * DR_ + tid];
  float m2 = block_sum(q, red) / DR_;
  float d2 = q - m2;
  float var2 = block_sum(d2 * d2, red) / DR_;
  float o = d2 * rsqrtf(var2 + 1e-5f) * ln2w[tid] + ln2b[tid];
  if (isnan(o)) o = 0.f; else if (isinf(o)) o = (o > 0.f) ? 1.f : -1.f;
  float nr = block_sum(o * o, red);
  float inv = 1.f / fmaxf(sqrtf(nr), 1e-6f);
  region[(long)row * DR_ + tid] = o * inv;
}

// ---------------- R3: in_proj (512 -> 1024), 4 rows/block ------------------
__global__ void k_inproj(const float* __restrict__ region, const float* __restrict__ W,
                         float* __restrict__ u, float* __restrict__ z){
  __shared__ float rr[4][DR_];
  int tid = threadIdx.x;
  int r0 = blockIdx.x * 4;
#pragma unroll
  for (int i = 0; i < 4; ++i) rr[i][tid] = region[(long)(r0 + i) * DR_ + tid];
  __syncthreads();
  float a[4] = {0,0,0,0}, b[4] = {0,0,0,0};
  for (int k = 0; k < DR_; ++k){
    float w1 = W[k * 1024 + tid];
    float w2v = W[k * 1024 + tid + 512];
#pragma unroll
    for (int i = 0; i < 4; ++i){ float x = rr[i][k]; a[i] += x * w1; b[i] += x * w2v; }
  }
#pragma unroll
  for (int i = 0; i < 4; ++i){
    u[(long)(r0 + i) * DR_ + tid] = a[i];
    z[(long)(r0 + i) * DR_ + tid] = b[i];
  }
}

// ---------------- R4: x_proj + dt head -> delta, Bm, Cm (padded to 64) -----
__global__ void k_xproj(const float* __restrict__ u, const float* __restrict__ xp,
                        const float* __restrict__ dtw, const float* __restrict__ dtb,
                        float* __restrict__ delta, float* __restrict__ Bm, float* __restrict__ Cm){
  __shared__ float ur[DR_];
  __shared__ float prm[RK_ + 2 * N_];
  int row = blockIdx.x, tid = threadIdx.x;
  ur[tid] = u[(long)row * DR_ + tid];
  __syncthreads();
  if (tid < RK_ + 2 * N_){
    float a = 0.f;
    for (int k = 0; k < DR_; ++k) a += ur[k] * xp[k * (RK_ + 2 * N_) + tid];
    prm[tid] = a;
  }
  __syncthreads();
  float a = dtb[tid];
#pragma unroll
  for (int j = 0; j < RK_; ++j) a += prm[j] * dtw[j * DR_ + tid];
  float sp = (a > 20.f) ? a : log1pf(expf(a));
  delta[(long)row * DR_ + tid] = fminf(sp, 10.f);
  if (tid < 64)       Bm[row * 64 + tid] = (tid < N_) ? prm[RK_ + tid] : 0.f;
  else if (tid < 128){ int i = tid - 64; Cm[row * 64 + i] = (i < N_) ? prm[RK_ + N_ + i] : 0.f; }
}

// ---------------- R5: selective scan; wave = (b,d), lane = n ---------------
__global__ void k_scan(const float* __restrict__ delta, const float* __restrict__ u,
                       const float* __restrict__ z, const float* __restrict__ Bm,
                       const float* __restrict__ Cm, const float* __restrict__ alog,
                       const float* __restrict__ Dp, float* __restrict__ ys){
  int tid = threadIdx.x, lane = tid & 63;
  int wid = blockIdx.x * 4 + (tid >> 6);
  int b = wid >> 9, d = wid & 511;
  float An = 0.f;
  if (lane < N_) An = -fminf(expf(alog[d * N_ + lane]), 10000.f);
  float Dd = Dp[d];
  float h = 0.f;
  for (int l = 0; l < R_; ++l){
    long rb = (long)(b * R_ + l);
    float dl = delta[rb * DR_ + d];
    float uu = u[rb * DR_ + d];
    float zz = z[rb * DR_ + d];
    float bm = Bm[rb * 64 + lane];
    float cm = Cm[rb * 64 + lane];
    float c = fminf(fmaxf(dl * An, -30.f), 30.f);
    float dA = expf(c);
    h = dA * h + dl * bm * uu;
    float part = cm * h;
#pragma unroll
    for (int m = 1; m < 64; m <<= 1) part += __shfl_xor(part, m, 64);
    if (lane == 0){
      float yv = part + Dd * uu;
      float sz = zz / (1.f + expf(-zz));
      ys[rb * DR_ + d] = yv * sz;
    }
  }
}

// ---------------- R6: out_proj + residual + final LN + l2norm --------------
__global__ void k_out(const float* __restrict__ ys, const float* __restrict__ W,
                      const float* __restrict__ region, const float* __restrict__ lnw,
                      const float* __restrict__ lnb, float* __restrict__ outp,
                      float* __restrict__ rt){
  __shared__ float yr[DR_];
  __shared__ float red[9];
  int row = blockIdx.x, tid = threadIdx.x;
  yr[tid] = ys[(long)row * DR_ + tid];
  __syncthreads();
  float y = 0.f;
  for (int k = 0; k < DR_; ++k) y += yr[k] * W[k * DR_ + tid];
  if (isnan(y)) y = 0.f; else if (isinf(y)) y = (y > 0.f) ? 1.f : -1.f;
  float v = region[(long)row * DR_ + tid] + y;
  float mean = block_sum(v, red) / DR_;
  float dv = v - mean;
  float var = block_sum(dv * dv, red) / DR_;
  float o = dv * rsqrtf(var + 1e-5f) * lnw[tid] + lnb[tid];
  outp[(long)row * DR_ + tid] = o;
  float nr = block_sum(o * o, red);
  float inv = 1.f / fmaxf(sqrtf(nr), 1e-6f);
  rt[(long)row * DR_ + tid] = o * inv;
}

// ---------------- R7: similarity losses ------------------------------------
__global__ void k_loss(const float* __restrict__ rt, const int* __restrict__ nearm,
                       const int* __restrict__ farm, float* __restrict__ accum){
  __shared__ __align__(16) float ar[DR_];
  __shared__ float wsum[4][4];
  int blk = blockIdx.x, tid = threadIdx.x;
  int b = blk >> 8, r = blk & 255;
  const float* rtb = rt + (long)b * R_ * DR_;
  ar[tid] = rtb[(long)r * DR_ + tid];
  ar[tid + 256] = rtb[(long)r * DR_ + tid + 256];
  __syncthreads();
  int s = tid;
  const float* rsrow = rtb + (long)s * DR_;
  float dot = 0.f;
  for (int k = 0; k < DR_; k += 4){
    float4 x = *(const float4*)(ar + k);
    float4 yv = *(const float4*)(rsrow + k);
    dot += x.x * yv.x + x.y * yv.y + x.z * yv.z + x.w * yv.w;
  }
  int nm = nearm[r * R_ + s], fm = farm[r * R_ + s];
  float nl = nm ? (1.f - dot) : 0.f;
  float fl = fm ? fmaxf(dot - 0.2f, 0.f) : 0.f;
  float nc = (b == 0 && nm) ? 1.f : 0.f;
  float fc = (b == 0 && fm) ? 1.f : 0.f;
  nl = wred_sum(nl); fl = wred_sum(fl); nc = wred_sum(nc); fc = wred_sum(fc);
  int w = tid >> 6, lane = tid & 63;
  if (lane == 0){ wsum[w][0] = nl; wsum[w][1] = fl; wsum[w][2] = nc; wsum[w][3] = fc; }
  __syncthreads();
  if (tid == 0){
    float a0 = 0, a1 = 0, a2 = 0, a3 = 0;
    for (int i = 0; i < 4; i++){ a0 += wsum[i][0]; a1 += wsum[i][1]; a2 += wsum[i][2]; a3 += wsum[i][3]; }
    atomicAdd(&accum[0], a0); atomicAdd(&accum[1], a1);
    if (b == 0){ atomicAdd(&accum[2], a2); atomicAdd(&accum[3], a3); }
  }
}

__global__ void k_final(const float* __restrict__ accum, float* __restrict__ outp){
  if (threadIdx.x == 0){
    float loss = accum[0] / fmaxf(accum[2], 1.f) + accum[1] / fmaxf(accum[3], 1.f);
    outp[REGS * DR_] = loss;
  }
}

extern "C" void kernel_launch(void* const* d_in, const int* in_sizes, int n_in,
                              void* d_out, int out_size, void* d_ws, size_t ws_size,
                              hipStream_t stream){
  const float* pt    = (const float*)d_in[0];
  const int*   pmask = (const int*)d_in[1];
  const int*   nearm = (const int*)d_in[2];
  const int*   farm  = (const int*)d_in[3];
  const float* lp    = (const float*)d_in[4];
  const float* glnw  = (const float*)d_in[5];
  const float* glnb  = (const float*)d_in[6];
  const float* gw1   = (const float*)d_in[7];
  const float* gb1   = (const float*)d_in[8];
  const float* gw2   = (const float*)d_in[9];
  const float* gb2   = (const float*)d_in[10];
  const float* pln1w = (const float*)d_in[11];
  const float* pln1b = (const float*)d_in[12];
  const float* pw1   = (const float*)d_in[13];
  const float* pb1   = (const float*)d_in[14];
  const float* pw2   = (const float*)d_in[15];
  const float* pb2   = (const float*)d_in[16];
  const float* pln2w = (const float*)d_in[17];
  const float* pln2b = (const float*)d_in[18];
  const float* inpw  = (const float*)d_in[19];
  const float* xpw   = (const float*)d_in[20];
  const float* dtw   = (const float*)d_in[21];
  const float* dtb   = (const float*)d_in[22];
  const float* alog  = (const float*)d_in[23];
  const float* dpar  = (const float*)d_in[24];
  const float* opw   = (const float*)d_in[25];
  const float* slnw  = (const float*)d_in[26];
  const float* slnb  = (const float*)d_in[27];

  char* ws = (char*)d_ws;
  size_t off = 0;
  auto alloc = [&](size_t bytes){ size_t o = off; off += (bytes + 255) & ~(size_t)255; return o; };
  ushort_t* W1pT = (ushort_t*)(ws + alloc((size_t)DR_ * DP_ * 2));
  float* s1     = (float*)(ws + alloc(DR_ * 4));
  float* b1p    = (float*)(ws + alloc(DR_ * 4));
  float* lpW    = (float*)(ws + alloc((size_t)P_ * DR_ * 4));
  float* mu     = (float*)(ws + alloc((size_t)MROWS * 4));
  float* rsg    = (float*)(ws + alloc((size_t)MROWS * 4));
  float* logits = (float*)(ws + alloc((size_t)MROWS * 4));
  float* pooled = (float*)(ws + alloc((size_t)REGS * DP_ * 4));
  float* region = (float*)(ws + alloc((size_t)REGS * DR_ * 4));
  float* u      = (float*)(ws + alloc((size_t)REGS * DR_ * 4));
  float* z      = (float*)(ws + alloc((size_t)REGS * DR_ * 4));
  float* delta  = (float*)(ws + alloc((size_t)REGS * DR_ * 4));
  float* Bm     = (float*)(ws + alloc((size_t)REGS * 64 * 4));
  float* Cm     = (float*)(ws + alloc((size_t)REGS * 64 * 4));
  float* ys     = (float*)(ws + alloc((size_t)REGS * DR_ * 4));
  float* rt     = (float*)(ws + alloc((size_t)REGS * DR_ * 4));
  float* accum  = (float*)(ws + alloc(4 * 4));

  float* outp = (float*)d_out;

  k_prep<<<dim3(8), dim3(64), 0, stream>>>(gw1, glnw, glnb, gb1, W1pT, s1, b1p, accum);
  k_lpw<<<dim3(P_), dim3(DR_), 0, stream>>>(lp, W1pT, lpW);
  k_stats<<<dim3(MROWS / 4), dim3(256), 0, stream>>>(pt, lp, mu, rsg);
  k_gate_gemm<<<dim3(MROWS / 64), dim3(512), 0, stream>>>(pt, W1pT, mu, rsg, s1, b1p, lpW, gw2, gb2, logits);
  k_pool<<<dim3(REGS), dim3(256), 0, stream>>>(pt, lp, logits, pmask, pooled);
  k_region_mlp<<<dim3(REGS), dim3(512), 0, stream>>>(pooled, pln1w, pln1b, pw1, pb1, pw2, pb2, pln2w, pln2b, region);
  k_inproj<<<dim3(REGS / 4), dim3(512), 0, stream>>>(region, inpw, u, z);
  k_xproj<<<dim3(REGS), dim3(512), 0, stream>>>(u, xpw, dtw, dtb, delta, Bm, Cm);
  k_scan<<<dim3(512), dim3(256), 0, stream>>>(delta, u, z, Bm, Cm, alog, dpar, ys);
  k_out<<<dim3(REGS), dim3(512), 0, stream>>>(ys, opw, region, slnw, slnb, outp, rt);
  k_loss<<<dim3(REGS), dim3(256), 0, stream>>>(rt, nearm, farm, accum);
  k_final<<<dim3(1), dim3(64), 0, stream>>>(accum, outp);
}

// Round 3
// 446.178 us; speedup vs baseline: 1.4454x; 1.4454x over previous
//
#include <hip/hip_runtime.h>
#include <hip/hip_bf16.h>
#include <math.h>

#define B_ 4
#define R_ 256
#define P_ 64
#define DP_ 384
#define DR_ 512
#define N_ 48
#define RK_ 24
#define MROWS (B_*R_*P_)   /* 65536 */
#define REGS  (B_*R_)      /* 1024  */

typedef unsigned short ushort_t;
typedef __attribute__((ext_vector_type(8))) short bf16x8;
typedef __attribute__((ext_vector_type(4))) float f32x4;

__device__ __forceinline__ float us2f(unsigned short u){
  union { unsigned int i; float f; } x; x.i = ((unsigned int)u) << 16; return x.f;
}
__device__ __forceinline__ unsigned short f2us(float f){
  __hip_bfloat16 h = __float2bfloat16(f);
  return *reinterpret_cast<unsigned short*>(&h);
}
__device__ __forceinline__ float gelu_f(float x){
  return 0.5f * x * (1.0f + erff(x * 0.70710678118654752f));
}
__device__ __forceinline__ float wred_sum(float v){
#pragma unroll
  for (int m = 1; m < 64; m <<= 1) v += __shfl_xor(v, m, 64);
  return v;
}
// block-wide sum; s must have >= 9 floats of LDS scratch
__device__ __forceinline__ float block_sum(float v, float* s){
  float w = wred_sum(v);
  int lane = threadIdx.x & 63, wid = threadIdx.x >> 6, nw = blockDim.x >> 6;
  if (lane == 0) s[wid] = w;
  __syncthreads();
  if (threadIdx.x == 0){ float t = 0.f; for (int i = 0; i < nw; i++) t += s[i]; s[8] = t; }
  __syncthreads();
  float r = s[8];
  __syncthreads();
  return r;
}
// 4 simultaneous block-wide sums (512-thread blocks); s >= 40 floats
__device__ __forceinline__ void block_sum4(float v[4], float* s){
  int lane = threadIdx.x & 63, wid = threadIdx.x >> 6;
#pragma unroll
  for (int i = 0; i < 4; ++i){
    float x = v[i];
#pragma unroll
    for (int m = 1; m < 64; m <<= 1) x += __shfl_xor(x, m, 64);
    if (lane == 0) s[wid * 4 + i] = x;
  }
  __syncthreads();
  if (threadIdx.x < 4){
    float t = 0.f;
    for (int t2 = 0; t2 < 8; ++t2) t += s[t2 * 4 + threadIdx.x];
    s[32 + threadIdx.x] = t;
  }
  __syncthreads();
#pragma unroll
  for (int i = 0; i < 4; ++i) v[i] = s[32 + i];
  __syncthreads();
}

// ---------------- C0: weight prep (W1pT bf16, s1, b1p) + zero loss accum ----
__global__ void k_prep(const float* __restrict__ gw1, const float* __restrict__ glnw,
                       const float* __restrict__ glnb, const float* __restrict__ gb1,
                       ushort_t* __restrict__ W1pT, float* __restrict__ s1,
                       float* __restrict__ b1p, float* __restrict__ accum){
  int n = blockIdx.x * 64 + threadIdx.x;   // 0..511
  if (blockIdx.x == 0 && threadIdx.x < 4) accum[threadIdx.x] = 0.f;
  float s = 0.f, sb = 0.f;
  for (int k = 0; k < DP_; ++k){
    float w1 = gw1[k * DR_ + n];
    float v = glnw[k] * w1;
    unsigned short vr = f2us(v);
    s  += us2f(vr);              // consistent with what the bf16 GEMM sees
    sb += glnb[k] * w1;
    W1pT[n * DP_ + k] = vr;
  }
  s1[n] = s;
  b1p[n] = gb1[n] + sb;
}

// ---- P2 fused: gate GEMM + LN-stats + folded LN + gelu + logit + softmax +
//      attention pooling. One block = one region (64 patch rows).
__global__ __launch_bounds__(512, 2) void k_gate_pool(
    const float* __restrict__ A,       // pt (65536 x 384) f32
    const float* __restrict__ lp,      // local_pos (64 x 384)
    const ushort_t* __restrict__ BT,   // W1pT (512 x 384) bf16
    const float* __restrict__ s1, const float* __restrict__ b1p,
    const float* __restrict__ w2, const int* __restrict__ pmask,
    float* __restrict__ pooled){
  __shared__ ushort_t As[64 * 64];
  __shared__ ushort_t Bs[512 * 64];
  __shared__ float logit_lds[64];
  __shared__ float smu[64], srs[64];
  __shared__ float attn[64];
  int tid = threadIdx.x;
  int lane = tid & 63, w = tid >> 6;
  int t = lane & 15, g = lane >> 4;
  long r0 = (long)blockIdx.x * 64;
  if (tid < 64) logit_lds[tid] = 0.f;

  f32x4 acc[4][4];
#pragma unroll
  for (int m = 0; m < 4; ++m)
#pragma unroll
    for (int n = 0; n < 4; ++n) acc[m][n] = (f32x4){0.f, 0.f, 0.f, 0.f};

  int arow = tid >> 3, acol = (tid & 7) * 8;
  const float* ag = A + (r0 + arow) * DP_ + acol;
  const float* lg = lp + arow * DP_ + acol;
  float sx = 0.f, sxx = 0.f;

  for (int kt = 0; kt < 6; ++kt){
    float4 a0 = *(const float4*)(ag + kt * 64);
    float4 a1 = *(const float4*)(ag + kt * 64 + 4);
    float4 l0 = *(const float4*)(lg + kt * 64);
    float4 l1 = *(const float4*)(lg + kt * 64 + 4);
    float xv[8] = {a0.x + l0.x, a0.y + l0.y, a0.z + l0.z, a0.w + l0.w,
                   a1.x + l1.x, a1.y + l1.y, a1.z + l1.z, a1.w + l1.w};
    bf16x8 ar;
#pragma unroll
    for (int i2 = 0; i2 < 8; ++i2){
      sx += xv[i2]; sxx += xv[i2] * xv[i2];
      ar[i2] = (short)f2us(xv[i2]);
    }
    bf16x8 br[8];
#pragma unroll
    for (int j = 0; j < 8; ++j){
      int nb = j * 64 + (tid >> 3);
      br[j] = *(const bf16x8*)(BT + nb * DP_ + kt * 64 + acol);
    }
    __syncthreads();
    *(bf16x8*)(As + tid * 8) = ar;
#pragma unroll
    for (int j = 0; j < 8; ++j) *(bf16x8*)(Bs + (j * 512 + tid) * 8) = br[j];
    __syncthreads();
#pragma unroll
    for (int kk = 0; kk < 2; ++kk){
      bf16x8 af[4], bfr[4];
      int ko = kk * 32 + g * 8;
#pragma unroll
      for (int m = 0; m < 4; ++m) af[m]  = *(const bf16x8*)(As + (m * 16 + t) * 64 + ko);
#pragma unroll
      for (int n = 0; n < 4; ++n) bfr[n] = *(const bf16x8*)(Bs + (w * 64 + n * 16 + t) * 64 + ko);
#pragma unroll
      for (int m = 0; m < 4; ++m)
#pragma unroll
        for (int n = 0; n < 4; ++n)
          acc[m][n] = __builtin_amdgcn_mfma_f32_16x16x32_bf16(af[m], bfr[n], acc[m][n], 0, 0, 0);
    }
  }
  // LN row stats: reduce across the 8 threads sharing a row (tid bits 0-2)
  sx  += __shfl_xor(sx, 1, 64);  sx += __shfl_xor(sx, 2, 64);  sx += __shfl_xor(sx, 4, 64);
  sxx += __shfl_xor(sxx, 1, 64); sxx += __shfl_xor(sxx, 2, 64); sxx += __shfl_xor(sxx, 4, 64);
  if ((tid & 7) == 0){
    float m = sx * (1.f / DP_);
    float var = sxx * (1.f / DP_) - m * m;
    smu[arow] = m;
    srs[arow] = rsqrtf(var + 1e-5f);
  }
  __syncthreads();

  // epilogue: folded LN + gelu + reduce against gate_w2
  float w2c[4], s1c[4], b1c[4];
#pragma unroll
  for (int n = 0; n < 4; ++n){
    int c = w * 64 + n * 16 + t;
    w2c[n] = w2[c]; s1c[n] = s1[c]; b1c[n] = b1p[c];
  }
#pragma unroll
  for (int m = 0; m < 4; ++m){
#pragma unroll
    for (int j = 0; j < 4; ++j){
      int rl = m * 16 + g * 4 + j;           // local row == p
      float mur = smu[rl], rs = srs[rl];
      float part = 0.f;
#pragma unroll
      for (int n = 0; n < 4; ++n){
        float gp = rs * acc[m][n][j] - mur * rs * s1c[n] + b1c[n];
        part += gelu_f(gp) * w2c[n];
      }
#pragma unroll
      for (int msk = 1; msk < 16; msk <<= 1) part += __shfl_xor(part, msk, 64);
      if (t == 0) atomicAdd(&logit_lds[rl], part);
    }
  }
  __syncthreads();

  // masked softmax over the 64 patches (gate_b2 cancels in softmax)
  if (tid < 64){
    int mk = pmask[r0 + tid];
    float lv = logit_lds[tid];
    float lm = mk ? lv : -3.4e38f;
    float M = lm;
#pragma unroll
    for (int m2 = 1; m2 < 64; m2 <<= 1) M = fmaxf(M, __shfl_xor(M, m2, 64));
    float e = mk ? __expf(lv - M) : 0.f;
    float S = e;
#pragma unroll
    for (int m2 = 1; m2 < 64; m2 <<= 1) S += __shfl_xor(S, m2, 64);
    float a = (S > 0.f) ? e / S : 0.f;
    float S2 = a;
#pragma unroll
    for (int m2 = 1; m2 < 64; m2 <<= 1) S2 += __shfl_xor(S2, m2, 64);
    attn[tid] = a / fmaxf(S2, 1e-6f);
  }
  __syncthreads();

  // attention pooling (pt/lp re-reads are L1/L2-hot)
  if (tid < DP_){
    float accp = 0.f;
    for (int p = 0; p < P_; ++p)
      accp += attn[p] * (A[(r0 + p) * DP_ + tid] + lp[p * DP_ + tid]);
    pooled[(long)blockIdx.x * DP_ + tid] = accp;
  }
}

// ---------------- R1: region MLP, 4 rows per block -------------------------
__global__ __launch_bounds__(512) void k_region_mlp(
    const float* __restrict__ pooled,
    const float* __restrict__ ln1w, const float* __restrict__ ln1b,
    const float* __restrict__ pw1, const float* __restrict__ pb1,
    const float* __restrict__ pw2, const float* __restrict__ pb2,
    const float* __restrict__ ln2w, const float* __restrict__ ln2b,
    float* __restrict__ region){
  __shared__ float xr[4][DP_];
  __shared__ float p1[4][DR_];
  __shared__ float red[40];
  int tid = threadIdx.x;
  int r0 = blockIdx.x * 4;
  for (int i = tid; i < 4 * DP_; i += 512) xr[i / DP_][i % DP_] = pooled[(long)r0 * DP_ + i];
  __syncthreads();
  float v[4], t4[4];
#pragma unroll
  for (int i = 0; i < 4; ++i){ v[i] = (tid < DP_) ? xr[i][tid] : 0.f; t4[i] = v[i]; }
  block_sum4(t4, red);
  float dv[4];
#pragma unroll
  for (int i = 0; i < 4; ++i){ dv[i] = (tid < DP_) ? (v[i] - t4[i] * (1.f / DP_)) : 0.f; t4[i] = dv[i] * dv[i]; }
  block_sum4(t4, red);
  float lw = (tid < DP_) ? ln1w[tid] : 0.f, lb = (tid < DP_) ? ln1b[tid] : 0.f;
  if (tid < DP_){
#pragma unroll
    for (int i = 0; i < 4; ++i)
      xr[i][tid] = dv[i] * rsqrtf(t4[i] * (1.f / DP_) + 1e-5f) * lw + lb;
  }
  __syncthreads();
  float a[4];
  float pb = pb1[tid];
#pragma unroll
  for (int i = 0; i < 4; ++i) a[i] = pb;
  for (int k = 0; k < DP_; ++k){
    float wv = pw1[k * DR_ + tid];
#pragma unroll
    for (int i = 0; i < 4; ++i) a[i] += xr[i][k] * wv;
  }
#pragma unroll
  for (int i = 0; i < 4; ++i) p1[i][tid] = gelu_f(a[i]);
  __syncthreads();
  float q[4];
  float pbb = pb2[tid];
#pragma unroll
  for (int i = 0; i < 4; ++i) q[i] = pbb;
  for (int k = 0; k < DR_; ++k){
    float wv = pw2[k * DR_ + tid];
#pragma unroll
    for (int i = 0; i < 4; ++i) q[i] += p1[i][k] * wv;
  }
#pragma unroll
  for (int i = 0; i < 4; ++i) t4[i] = q[i];
  block_sum4(t4, red);
  float d2[4];
#pragma unroll
  for (int i = 0; i < 4; ++i){ d2[i] = q[i] - t4[i] * (1.f / DR_); t4[i] = d2[i] * d2[i]; }
  block_sum4(t4, red);
  float o[4];
  float l2w = ln2w[tid], l2b = ln2b[tid];
#pragma unroll
  for (int i = 0; i < 4; ++i){
    o[i] = d2[i] * rsqrtf(t4[i] * (1.f / DR_) + 1e-5f) * l2w + l2b;
    if (isnan(o[i])) o[i] = 0.f; else if (isinf(o[i])) o[i] = (o[i] > 0.f) ? 1.f : -1.f;
    t4[i] = o[i] * o[i];
  }
  block_sum4(t4, red);
#pragma unroll
  for (int i = 0; i < 4; ++i)
    region[(long)(r0 + i) * DR_ + tid] = o[i] / fmaxf(sqrtf(t4[i]), 1e-6f);
}

// ---------------- R3: in_proj (512 -> 1024), 4 rows/block ------------------
__global__ void k_inproj(const float* __restrict__ region, const float* __restrict__ W,
                         float* __restrict__ u, float* __restrict__ z){
  __shared__ float rr[4][DR_];
  int tid = threadIdx.x;
  int r0 = blockIdx.x * 4;
#pragma unroll
  for (int i = 0; i < 4; ++i) rr[i][tid] = region[(long)(r0 + i) * DR_ + tid];
  __syncthreads();
  float a[4] = {0,0,0,0}, b[4] = {0,0,0,0};
  for (int k = 0; k < DR_; ++k){
    float w1 = W[k * 1024 + tid];
    float w2v = W[k * 1024 + tid + 512];
#pragma unroll
    for (int i = 0; i < 4; ++i){ float x = rr[i][k]; a[i] += x * w1; b[i] += x * w2v; }
  }
#pragma unroll
  for (int i = 0; i < 4; ++i){
    u[(long)(r0 + i) * DR_ + tid] = a[i];
    z[(long)(r0 + i) * DR_ + tid] = b[i];
  }
}

// ---------------- R4: x_proj + dt head -> delta, Bm, Cm (padded to 64) -----
__global__ void k_xproj(const float* __restrict__ u, const float* __restrict__ xp,
                        const float* __restrict__ dtw, const float* __restrict__ dtb,
                        float* __restrict__ delta, float* __restrict__ Bm, float* __restrict__ Cm){
  __shared__ float ur[DR_];
  __shared__ float prm[RK_ + 2 * N_];
  int row = blockIdx.x, tid = threadIdx.x;
  ur[tid] = u[(long)row * DR_ + tid];
  __syncthreads();
  if (tid < RK_ + 2 * N_){
    float a = 0.f;
    for (int k = 0; k < DR_; ++k) a += ur[k] * xp[k * (RK_ + 2 * N_) + tid];
    prm[tid] = a;
  }
  __syncthreads();
  float a = dtb[tid];
#pragma unroll
  for (int j = 0; j < RK_; ++j) a += prm[j] * dtw[j * DR_ + tid];
  float sp = (a > 20.f) ? a : log1pf(expf(a));
  delta[(long)row * DR_ + tid] = fminf(sp, 10.f);
  if (tid < 64)       Bm[row * 64 + tid] = (tid < N_) ? prm[RK_ + tid] : 0.f;
  else if (tid < 128){ int i = tid - 64; Cm[row * 64 + i] = (i < N_) ? prm[RK_ + N_ + i] : 0.f; }
}

// ---------------- R5: parallel-prefix selective scan -----------------------
// block = (b,d) channel; thread = sequence position l (256 = 4 waves x 64).
// Per state n: Kogge-Stone scan of h_l = a_l h_{l-1} + b_l within each wave,
// cross-wave carry via LDS tile summaries. Output accumulates in-lane.
__global__ __launch_bounds__(256) void k_scan(
    const float* __restrict__ delta, const float* __restrict__ u,
    const float* __restrict__ z, const float* __restrict__ Bm,
    const float* __restrict__ Cm, const float* __restrict__ alog,
    const float* __restrict__ Dp, float* __restrict__ ys){
  __shared__ float sAn[N_];
  __shared__ float sA[N_][4];
  __shared__ float sB[N_][4];
  int tid = threadIdx.x, lane = tid & 63, w = tid >> 6;
  int ch = blockIdx.x;
  int b = ch >> 9, d = ch & (DR_ - 1);
  if (tid < N_) sAn[tid] = -fminf(__expf(alog[d * N_ + tid]), 10000.f);
  long rb = (long)b * R_ + tid;
  float dl = delta[rb * DR_ + d];
  float uu = u[rb * DR_ + d];
  float zz = z[rb * DR_ + d];
  const float* bmrow = Bm + rb * 64;
  const float* cmrow = Cm + rb * 64;
  float Dd = Dp[d];
  float part = 0.f;
  __syncthreads();
  for (int nc = 0; nc < 6; ++nc){
    float4 bm0 = *(const float4*)(bmrow + nc * 8);
    float4 bm1 = *(const float4*)(bmrow + nc * 8 + 4);
    float4 cm0 = *(const float4*)(cmrow + nc * 8);
    float4 cm1 = *(const float4*)(cmrow + nc * 8 + 4);
    float bmv[8] = {bm0.x,bm0.y,bm0.z,bm0.w,bm1.x,bm1.y,bm1.z,bm1.w};
    float cmv[8] = {cm0.x,cm0.y,cm0.z,cm0.w,cm1.x,cm1.y,cm1.z,cm1.w};
    float aA[8], aB[8];
#pragma unroll
    for (int j = 0; j < 8; ++j){
      int n = nc * 8 + j;
      float c = fminf(fmaxf(dl * sAn[n], -30.f), 30.f);
      float a = exp2f(c * 1.44269504f);
      float bv = dl * bmv[j] * uu;
#pragma unroll
      for (int s = 1; s < 64; s <<= 1){
        float a_sh = __shfl_up(a, (unsigned)s, 64);
        float b_sh = __shfl_up(bv, (unsigned)s, 64);
        float nb = fmaf(a, b_sh, bv);
        float na = a * a_sh;
        if (lane >= s){ bv = nb; a = na; }
      }
      aA[j] = a; aB[j] = bv;
      if (lane == 63){ sA[n][w] = a; sB[n][w] = bv; }
    }
    __syncthreads();
#pragma unroll
    for (int j = 0; j < 8; ++j){
      int n = nc * 8 + j;
      float hin = 0.f;
#pragma unroll
      for (int tt = 0; tt < 3; ++tt){
        if (tt < w) hin = sA[n][tt] * hin + sB[n][tt];
      }
      float h = fmaf(aA[j], hin, aB[j]);
      part = fmaf(cmv[j], h, part);
    }
  }
  float yv = part + Dd * uu;
  float sz = zz / (1.f + __expf(-zz));
  ys[rb * DR_ + d] = yv * sz;
}

// ---------------- R6: out_proj + residual + final LN + l2norm, 4 rows ------
__global__ __launch_bounds__(512) void k_out(
    const float* __restrict__ ys, const float* __restrict__ W,
    const float* __restrict__ region, const float* __restrict__ lnw,
    const float* __restrict__ lnb, float* __restrict__ outp,
    float* __restrict__ rt){
  __shared__ float yr[4][DR_];
  __shared__ float red[40];
  int tid = threadIdx.x;
  int r0 = blockIdx.x * 4;
  for (int i = tid; i < 4 * DR_; i += 512) yr[i >> 9][i & 511] = ys[(long)r0 * DR_ + i];
  __syncthreads();
  float y[4] = {0,0,0,0};
  for (int k = 0; k < DR_; ++k){
    float wv = W[k * DR_ + tid];
#pragma unroll
    for (int i = 0; i < 4; ++i) y[i] += yr[i][k] * wv;
  }
  float v[4], t4[4];
#pragma unroll
  for (int i = 0; i < 4; ++i){
    if (isnan(y[i])) y[i] = 0.f; else if (isinf(y[i])) y[i] = (y[i] > 0.f) ? 1.f : -1.f;
    v[i] = region[(long)(r0 + i) * DR_ + tid] + y[i];
    t4[i] = v[i];
  }
  block_sum4(t4, red);
  float dv[4];
#pragma unroll
  for (int i = 0; i < 4; ++i){ dv[i] = v[i] - t4[i] * (1.f / DR_); t4[i] = dv[i] * dv[i]; }
  block_sum4(t4, red);
  float o[4];
  float lw = lnw[tid], lb = lnb[tid];
#pragma unroll
  for (int i = 0; i < 4; ++i){
    o[i] = dv[i] * rsqrtf(t4[i] * (1.f / DR_) + 1e-5f) * lw + lb;
    outp[(long)(r0 + i) * DR_ + tid] = o[i];
    t4[i] = o[i] * o[i];
  }
  block_sum4(t4, red);
#pragma unroll
  for (int i = 0; i < 4; ++i)
    rt[(long)(r0 + i) * DR_ + tid] = o[i] / fmaxf(sqrtf(t4[i]), 1e-6f);
}

// ---------------- R7: similarity losses ------------------------------------
__global__ void k_loss(const float* __restrict__ rt, const int* __restrict__ nearm,
                       const int* __restrict__ farm, float* __restrict__ accum){
  __shared__ __align__(16) float ar[DR_];
  __shared__ float wsum[4][4];
  int blk = blockIdx.x, tid = threadIdx.x;
  int b = blk >> 8, r = blk & 255;
  const float* rtb = rt + (long)b * R_ * DR_;
  ar[tid] = rtb[(long)r * DR_ + tid];
  ar[tid + 256] = rtb[(long)r * DR_ + tid + 256];
  __syncthreads();
  int s = tid;
  const float* rsrow = rtb + (long)s * DR_;
  float dot = 0.f;
  for (int k = 0; k < DR_; k += 4){
    float4 x = *(const float4*)(ar + k);
    float4 yv = *(const float4*)(rsrow + k);
    dot += x.x * yv.x + x.y * yv.y + x.z * yv.z + x.w * yv.w;
  }
  int nm = nearm[r * R_ + s], fm = farm[r * R_ + s];
  float nl = nm ? (1.f - dot) : 0.f;
  float fl = fm ? fmaxf(dot - 0.2f, 0.f) : 0.f;
  float nc = (b == 0 && nm) ? 1.f : 0.f;
  float fc = (b == 0 && fm) ? 1.f : 0.f;
  nl = wred_sum(nl); fl = wred_sum(fl); nc = wred_sum(nc); fc = wred_sum(fc);
  int w = tid >> 6, lane = tid & 63;
  if (lane == 0){ wsum[w][0] = nl; wsum[w][1] = fl; wsum[w][2] = nc; wsum[w][3] = fc; }
  __syncthreads();
  if (tid == 0){
    float a0 = 0, a1 = 0, a2 = 0, a3 = 0;
    for (int i = 0; i < 4; i++){ a0 += wsum[i][0]; a1 += wsum[i][1]; a2 += wsum[i][2]; a3 += wsum[i][3]; }
    atomicAdd(&accum[0], a0); atomicAdd(&accum[1], a1);
    if (b == 0){ atomicAdd(&accum[2], a2); atomicAdd(&accum[3], a3); }
  }
}

__global__ void k_final(const float* __restrict__ accum, float* __restrict__ outp){
  if (threadIdx.x == 0){
    float loss = accum[0] / fmaxf(accum[2], 1.f) + accum[1] / fmaxf(accum[3], 1.f);
    outp[REGS * DR_] = loss;
  }
}

extern "C" void kernel_launch(void* const* d_in, const int* in_sizes, int n_in,
                              void* d_out, int out_size, void* d_ws, size_t ws_size,
                              hipStream_t stream){
  const float* pt    = (const float*)d_in[0];
  const int*   pmask = (const int*)d_in[1];
  const int*   nearm = (const int*)d_in[2];
  const int*   farm  = (const int*)d_in[3];
  const float* lp    = (const float*)d_in[4];
  const float* glnw  = (const float*)d_in[5];
  const float* glnb  = (const float*)d_in[6];
  const float* gw1   = (const float*)d_in[7];
  const float* gb1   = (const float*)d_in[8];
  const float* gw2   = (const float*)d_in[9];
  const float* pln1w = (const float*)d_in[11];
  const float* pln1b = (const float*)d_in[12];
  const float* pw1   = (const float*)d_in[13];
  const float* pb1   = (const float*)d_in[14];
  const float* pw2   = (const float*)d_in[15];
  const float* pb2   = (const float*)d_in[16];
  const float* pln2w = (const float*)d_in[17];
  const float* pln2b = (const float*)d_in[18];
  const float* inpw  = (const float*)d_in[19];
  const float* xpw   = (const float*)d_in[20];
  const float* dtw   = (const float*)d_in[21];
  const float* dtb   = (const float*)d_in[22];
  const float* alog  = (const float*)d_in[23];
  const float* dpar  = (const float*)d_in[24];
  const float* opw   = (const float*)d_in[25];
  const float* slnw  = (const float*)d_in[26];
  const float* slnb  = (const float*)d_in[27];

  char* ws = (char*)d_ws;
  size_t off = 0;
  auto alloc = [&](size_t bytes){ size_t o = off; off += (bytes + 255) & ~(size_t)255; return o; };
  ushort_t* W1pT = (ushort_t*)(ws + alloc((size_t)DR_ * DP_ * 2));
  float* s1     = (float*)(ws + alloc(DR_ * 4));
  float* b1p    = (float*)(ws + alloc(DR_ * 4));
  float* pooled = (float*)(ws + alloc((size_t)REGS * DP_ * 4));
  float* region = (float*)(ws + alloc((size_t)REGS * DR_ * 4));
  float* u      = (float*)(ws + alloc((size_t)REGS * DR_ * 4));
  float* z      = (float*)(ws + alloc((size_t)REGS * DR_ * 4));
  float* delta  = (float*)(ws + alloc((size_t)REGS * DR_ * 4));
  float* Bm     = (float*)(ws + alloc((size_t)REGS * 64 * 4));
  float* Cm     = (float*)(ws + alloc((size_t)REGS * 64 * 4));
  float* ys     = (float*)(ws + alloc((size_t)REGS * DR_ * 4));
  float* rt     = (float*)(ws + alloc((size_t)REGS * DR_ * 4));
  float* accum  = (float*)(ws + alloc(4 * 4));

  float* outp = (float*)d_out;

  k_prep<<<dim3(8), dim3(64), 0, stream>>>(gw1, glnw, glnb, gb1, W1pT, s1, b1p, accum);
  k_gate_pool<<<dim3(REGS), dim3(512), 0, stream>>>(pt, lp, W1pT, s1, b1p, gw2, pmask, pooled);
  k_region_mlp<<<dim3(REGS / 4), dim3(512), 0, stream>>>(pooled, pln1w, pln1b, pw1, pb1, pw2, pb2, pln2w, pln2b, region);
  k_inproj<<<dim3(REGS / 4), dim3(512), 0, stream>>>(region, inpw, u, z);
  k_xproj<<<dim3(REGS), dim3(512), 0, stream>>>(u, xpw, dtw, dtb, delta, Bm, Cm);
  k_scan<<<dim3(B_ * DR_), dim3(256), 0, stream>>>(delta, u, z, Bm, Cm, alog, dpar, ys);
  k_out<<<dim3(REGS / 4), dim3(512), 0, stream>>>(ys, opw, region, slnw, slnb, outp, rt);
  k_loss<<<dim3(REGS), dim3(256), 0, stream>>>(rt, nearm, farm, accum);
  k_final<<<dim3(1), dim3(64), 0, stream>>>(accum, outp);
}

// Round 4
// 393.236 us; speedup vs baseline: 1.6400x; 1.1346x over previous
//
#include <hip/hip_runtime.h>
#include <hip/hip_bf16.h>
#include <math.h>

#define B_ 4
#define R_ 256
#define P_ 64
#define DP_ 384
#define DR_ 512
#define N_ 48
#define RK_ 24
#define MROWS (B_*R_*P_)   /* 65536 */
#define REGS  (B_*R_)      /* 1024  */

typedef unsigned short ushort_t;
typedef __attribute__((ext_vector_type(8))) short bf16x8;
typedef __attribute__((ext_vector_type(4))) float f32x4;

__device__ __forceinline__ float us2f(unsigned short u){
  union { unsigned int i; float f; } x; x.i = ((unsigned int)u) << 16; return x.f;
}
__device__ __forceinline__ unsigned short f2us(float f){
  __hip_bfloat16 h = __float2bfloat16(f);
  return *reinterpret_cast<unsigned short*>(&h);
}
__device__ __forceinline__ float gelu_f(float x){
  return 0.5f * x * (1.0f + erff(x * 0.70710678118654752f));
}
__device__ __forceinline__ float wred_sum(float v){
#pragma unroll
  for (int m = 1; m < 64; m <<= 1) v += __shfl_xor(v, m, 64);
  return v;
}
// 4 simultaneous block-wide sums (512-thread blocks); s >= 40 floats
__device__ __forceinline__ void block_sum4(float v[4], float* s){
  int lane = threadIdx.x & 63, wid = threadIdx.x >> 6;
#pragma unroll
  for (int i = 0; i < 4; ++i){
    float x = v[i];
#pragma unroll
    for (int m = 1; m < 64; m <<= 1) x += __shfl_xor(x, m, 64);
    if (lane == 0) s[wid * 4 + i] = x;
  }
  __syncthreads();
  if (threadIdx.x < 4){
    float t = 0.f;
    for (int t2 = 0; t2 < 8; ++t2) t += s[t2 * 4 + threadIdx.x];
    s[32 + threadIdx.x] = t;
  }
  __syncthreads();
#pragma unroll
  for (int i = 0; i < 4; ++i) v[i] = s[32 + i];
  __syncthreads();
}

// ---------------- C0: weight prep (W1pT bf16, s1, b1p) + zero loss accum ----
__global__ void k_prep(const float* __restrict__ gw1, const float* __restrict__ glnw,
                       const float* __restrict__ glnb, const float* __restrict__ gb1,
                       ushort_t* __restrict__ W1pT, float* __restrict__ s1,
                       float* __restrict__ b1p, float* __restrict__ accum){
  int n = blockIdx.x * 64 + threadIdx.x;   // 0..511
  if (blockIdx.x == 0 && threadIdx.x < 4) accum[threadIdx.x] = 0.f;
  float s = 0.f, sb = 0.f;
  for (int k = 0; k < DP_; ++k){
    float w1 = gw1[k * DR_ + n];
    float v = glnw[k] * w1;
    unsigned short vr = f2us(v);
    s  += us2f(vr);              // consistent with what the bf16 GEMM sees
    sb += glnb[k] * w1;
    W1pT[n * DP_ + k] = vr;
  }
  s1[n] = s;
  b1p[n] = gb1[n] + sb;
}

// ---- P2 fused: gate GEMM + LN-stats + folded LN + gelu + logit + softmax +
//      attention pooling. One block = one region (64 patch rows).
//      LDS tiles XOR-swizzled (16-B chunk ^ row&7); next-K register prefetch.
__global__ __launch_bounds__(512, 2) void k_gate_pool(
    const float* __restrict__ A,       // pt (65536 x 384) f32
    const float* __restrict__ lp,      // local_pos (64 x 384)
    const ushort_t* __restrict__ BT,   // W1pT (512 x 384) bf16
    const float* __restrict__ s1, const float* __restrict__ b1p,
    const float* __restrict__ w2, const int* __restrict__ pmask,
    float* __restrict__ pooled){
  __shared__ ushort_t As[64 * 64];
  __shared__ ushort_t Bs[512 * 64];
  __shared__ float logit_lds[64];
  __shared__ float smu[64], srs[64];
  __shared__ float attn[64];
  int tid = threadIdx.x;
  int lane = tid & 63, w = tid >> 6;
  int t = lane & 15, g = lane >> 4;
  long r0 = (long)blockIdx.x * 64;
  if (tid < 64) logit_lds[tid] = 0.f;

  f32x4 acc[4][4];
#pragma unroll
  for (int m = 0; m < 4; ++m)
#pragma unroll
    for (int n = 0; n < 4; ++n) acc[m][n] = (f32x4){0.f, 0.f, 0.f, 0.f};

  int arow = tid >> 3, ac = tid & 7;
  int acol = ac * 8;
  const float* ag = A + (r0 + arow) * DP_ + acol;
  const float* lg = lp + arow * DP_ + acol;
  const ushort_t* bg = BT + (tid >> 3) * DP_ + acol;
  float sx = 0.f, sxx = 0.f;
  int wswz = (ac ^ (arow & 7)) * 8;    // swizzled chunk offset (ushort units)

  // prefetch kt = 0
  float4 a0 = *(const float4*)(ag);
  float4 a1 = *(const float4*)(ag + 4);
  float4 l0 = *(const float4*)(lg);
  float4 l1 = *(const float4*)(lg + 4);
  bf16x8 br[8];
#pragma unroll
  for (int j = 0; j < 8; ++j) br[j] = *(const bf16x8*)(bg + j * 64 * DP_);

  for (int kt = 0; kt < 6; ++kt){
    float xv[8] = {a0.x + l0.x, a0.y + l0.y, a0.z + l0.z, a0.w + l0.w,
                   a1.x + l1.x, a1.y + l1.y, a1.z + l1.z, a1.w + l1.w};
    bf16x8 ar;
#pragma unroll
    for (int i2 = 0; i2 < 8; ++i2){
      sx += xv[i2]; sxx += xv[i2] * xv[i2];
      ar[i2] = (short)f2us(xv[i2]);
    }
    __syncthreads();
    *(bf16x8*)(As + arow * 64 + wswz) = ar;
#pragma unroll
    for (int j = 0; j < 8; ++j)
      *(bf16x8*)(Bs + (j * 64 + arow) * 64 + wswz) = br[j];
    __syncthreads();
    if (kt < 5){
      a0 = *(const float4*)(ag + (kt + 1) * 64);
      a1 = *(const float4*)(ag + (kt + 1) * 64 + 4);
      l0 = *(const float4*)(lg + (kt + 1) * 64);
      l1 = *(const float4*)(lg + (kt + 1) * 64 + 4);
#pragma unroll
      for (int j = 0; j < 8; ++j)
        br[j] = *(const bf16x8*)(bg + j * 64 * DP_ + (kt + 1) * 64);
    }
#pragma unroll
    for (int kk = 0; kk < 2; ++kk){
      bf16x8 af[4], bfr[4];
      int ch = kk * 4 + g;
#pragma unroll
      for (int m = 0; m < 4; ++m){
        int row = m * 16 + t;
        af[m] = *(const bf16x8*)(As + row * 64 + ((ch ^ (row & 7)) * 8));
      }
#pragma unroll
      for (int n = 0; n < 4; ++n){
        int row = w * 64 + n * 16 + t;
        bfr[n] = *(const bf16x8*)(Bs + row * 64 + ((ch ^ (row & 7)) * 8));
      }
#pragma unroll
      for (int m = 0; m < 4; ++m)
#pragma unroll
        for (int n = 0; n < 4; ++n)
          acc[m][n] = __builtin_amdgcn_mfma_f32_16x16x32_bf16(af[m], bfr[n], acc[m][n], 0, 0, 0);
    }
  }
  // LN row stats: reduce across the 8 threads sharing a row (tid bits 0-2)
  sx  += __shfl_xor(sx, 1, 64);  sx += __shfl_xor(sx, 2, 64);  sx += __shfl_xor(sx, 4, 64);
  sxx += __shfl_xor(sxx, 1, 64); sxx += __shfl_xor(sxx, 2, 64); sxx += __shfl_xor(sxx, 4, 64);
  if ((tid & 7) == 0){
    float m = sx * (1.f / DP_);
    float var = sxx * (1.f / DP_) - m * m;
    smu[arow] = m;
    srs[arow] = rsqrtf(var + 1e-5f);
  }
  __syncthreads();

  // epilogue: folded LN + gelu + reduce against gate_w2
  float w2c[4], s1c[4], b1c[4];
#pragma unroll
  for (int n = 0; n < 4; ++n){
    int c = w * 64 + n * 16 + t;
    w2c[n] = w2[c]; s1c[n] = s1[c]; b1c[n] = b1p[c];
  }
#pragma unroll
  for (int m = 0; m < 4; ++m){
#pragma unroll
    for (int j = 0; j < 4; ++j){
      int rl = m * 16 + g * 4 + j;           // local row == p
      float mur = smu[rl], rs = srs[rl];
      float part = 0.f;
#pragma unroll
      for (int n = 0; n < 4; ++n){
        float gp = rs * acc[m][n][j] - mur * rs * s1c[n] + b1c[n];
        part += gelu_f(gp) * w2c[n];
      }
#pragma unroll
      for (int msk = 1; msk < 16; msk <<= 1) part += __shfl_xor(part, msk, 64);
      if (t == 0) atomicAdd(&logit_lds[rl], part);
    }
  }
  __syncthreads();

  // masked softmax over the 64 patches (gate_b2 cancels in softmax)
  if (tid < 64){
    int mk = pmask[r0 + tid];
    float lv = logit_lds[tid];
    float lm = mk ? lv : -3.4e38f;
    float M = lm;
#pragma unroll
    for (int m2 = 1; m2 < 64; m2 <<= 1) M = fmaxf(M, __shfl_xor(M, m2, 64));
    float e = mk ? __expf(lv - M) : 0.f;
    float S = e;
#pragma unroll
    for (int m2 = 1; m2 < 64; m2 <<= 1) S += __shfl_xor(S, m2, 64);
    float a = (S > 0.f) ? e / S : 0.f;
    float S2 = a;
#pragma unroll
    for (int m2 = 1; m2 < 64; m2 <<= 1) S2 += __shfl_xor(S2, m2, 64);
    attn[tid] = a / fmaxf(S2, 1e-6f);
  }
  __syncthreads();

  // attention pooling (pt/lp re-reads are L1/L2-hot)
  if (tid < DP_){
    float accp = 0.f;
    for (int p = 0; p < P_; ++p)
      accp += attn[p] * (A[(r0 + p) * DP_ + tid] + lp[p * DP_ + tid]);
    pooled[(long)blockIdx.x * DP_ + tid] = accp;
  }
}

// ---------------- R1: region MLP, 4 rows per block -------------------------
__global__ __launch_bounds__(512) void k_region_mlp(
    const float* __restrict__ pooled,
    const float* __restrict__ ln1w, const float* __restrict__ ln1b,
    const float* __restrict__ pw1, const float* __restrict__ pb1,
    const float* __restrict__ pw2, const float* __restrict__ pb2,
    const float* __restrict__ ln2w, const float* __restrict__ ln2b,
    float* __restrict__ region){
  __shared__ float xr[4][DP_];
  __shared__ float p1[4][DR_];
  __shared__ float red[40];
  int tid = threadIdx.x;
  int r0 = blockIdx.x * 4;
  for (int i = tid; i < 4 * DP_; i += 512) xr[i / DP_][i % DP_] = pooled[(long)r0 * DP_ + i];
  __syncthreads();
  float v[4], t4[4];
#pragma unroll
  for (int i = 0; i < 4; ++i){ v[i] = (tid < DP_) ? xr[i][tid] : 0.f; t4[i] = v[i]; }
  block_sum4(t4, red);
  float dv[4];
#pragma unroll
  for (int i = 0; i < 4; ++i){ dv[i] = (tid < DP_) ? (v[i] - t4[i] * (1.f / DP_)) : 0.f; t4[i] = dv[i] * dv[i]; }
  block_sum4(t4, red);
  float lw = (tid < DP_) ? ln1w[tid] : 0.f, lb = (tid < DP_) ? ln1b[tid] : 0.f;
  if (tid < DP_){
#pragma unroll
    for (int i = 0; i < 4; ++i)
      xr[i][tid] = dv[i] * rsqrtf(t4[i] * (1.f / DP_) + 1e-5f) * lw + lb;
  }
  __syncthreads();
  float a[4];
  float pb = pb1[tid];
#pragma unroll
  for (int i = 0; i < 4; ++i) a[i] = pb;
  for (int k = 0; k < DP_; ++k){
    float wv = pw1[k * DR_ + tid];
#pragma unroll
    for (int i = 0; i < 4; ++i) a[i] += xr[i][k] * wv;
  }
#pragma unroll
  for (int i = 0; i < 4; ++i) p1[i][tid] = gelu_f(a[i]);
  __syncthreads();
  float q[4];
  float pbb = pb2[tid];
#pragma unroll
  for (int i = 0; i < 4; ++i) q[i] = pbb;
  for (int k = 0; k < DR_; ++k){
    float wv = pw2[k * DR_ + tid];
#pragma unroll
    for (int i = 0; i < 4; ++i) q[i] += p1[i][k] * wv;
  }
#pragma unroll
  for (int i = 0; i < 4; ++i) t4[i] = q[i];
  block_sum4(t4, red);
  float d2[4];
#pragma unroll
  for (int i = 0; i < 4; ++i){ d2[i] = q[i] - t4[i] * (1.f / DR_); t4[i] = d2[i] * d2[i]; }
  block_sum4(t4, red);
  float o[4];
  float l2w = ln2w[tid], l2b = ln2b[tid];
#pragma unroll
  for (int i = 0; i < 4; ++i){
    o[i] = d2[i] * rsqrtf(t4[i] * (1.f / DR_) + 1e-5f) * l2w + l2b;
    if (isnan(o[i])) o[i] = 0.f; else if (isinf(o[i])) o[i] = (o[i] > 0.f) ? 1.f : -1.f;
    t4[i] = o[i] * o[i];
  }
  block_sum4(t4, red);
#pragma unroll
  for (int i = 0; i < 4; ++i)
    region[(long)(r0 + i) * DR_ + tid] = o[i] / fmaxf(sqrtf(t4[i]), 1e-6f);
}

// ---------------- R3: in_proj (512 -> 1024), 4 rows/block ------------------
// u written in both layouts; z only transposed (scan is its only consumer).
__global__ void k_inproj(const float* __restrict__ region, const float* __restrict__ W,
                         float* __restrict__ u, float* __restrict__ uT,
                         float* __restrict__ zT){
  __shared__ float rr[4][DR_];
  int tid = threadIdx.x;
  int r0 = blockIdx.x * 4;
#pragma unroll
  for (int i = 0; i < 4; ++i) rr[i][tid] = region[(long)(r0 + i) * DR_ + tid];
  __syncthreads();
  float a[4] = {0,0,0,0}, b[4] = {0,0,0,0};
  for (int k = 0; k < DR_; ++k){
    float w1 = W[k * 1024 + tid];
    float w2v = W[k * 1024 + tid + 512];
#pragma unroll
    for (int i = 0; i < 4; ++i){ float x = rr[i][k]; a[i] += x * w1; b[i] += x * w2v; }
  }
#pragma unroll
  for (int i = 0; i < 4; ++i){
    u[(long)(r0 + i) * DR_ + tid] = a[i];
    uT[(long)tid * REGS + r0 + i] = a[i];
    zT[(long)tid * REGS + r0 + i] = b[i];
  }
}

// ---------------- R4: x_proj + dt head, 2 rows/block, transposed outputs ---
__global__ __launch_bounds__(512) void k_xproj(
    const float* __restrict__ u, const float* __restrict__ xp,
    const float* __restrict__ dtw, const float* __restrict__ dtb,
    float* __restrict__ deltaT, float* __restrict__ BmT, float* __restrict__ CmT){
  __shared__ float ur[2][DR_];
  __shared__ float ps[4][2][128];
  __shared__ float prm[2][RK_ + 2 * N_];
  int tid = threadIdx.x;
  int row0 = blockIdx.x * 2;
  ur[0][tid] = u[(long)row0 * DR_ + tid];
  ur[1][tid] = u[(long)(row0 + 1) * DR_ + tid];
  __syncthreads();
  int c = tid & 127, s = tid >> 7;       // K-split GEMV: 4 segments x 128 cols
  float a0 = 0.f, a1 = 0.f;
  if (c < RK_ + 2 * N_){
    for (int k = s * 128; k < s * 128 + 128; ++k){
      float wv = xp[k * (RK_ + 2 * N_) + c];
      a0 += ur[0][k] * wv; a1 += ur[1][k] * wv;
    }
  }
  ps[s][0][c] = a0; ps[s][1][c] = a1;
  __syncthreads();
  if (tid < 256){
    int rr2 = tid >> 7, cc = tid & 127;
    if (cc < RK_ + 2 * N_)
      prm[rr2][cc] = ps[0][rr2][cc] + ps[1][rr2][cc] + ps[2][rr2][cc] + ps[3][rr2][cc];
  }
  __syncthreads();
#pragma unroll
  for (int r = 0; r < 2; ++r){
    float a = dtb[tid];
#pragma unroll
    for (int j = 0; j < RK_; ++j) a += prm[r][j] * dtw[j * DR_ + tid];
    float sp = (a > 20.f) ? a : log1pf(expf(a));
    deltaT[(long)tid * REGS + row0 + r] = fminf(sp, 10.f);
  }
  if (tid < N_){
    BmT[(long)tid * REGS + row0]     = prm[0][RK_ + tid];
    BmT[(long)tid * REGS + row0 + 1] = prm[1][RK_ + tid];
    CmT[(long)tid * REGS + row0]     = prm[0][RK_ + N_ + tid];
    CmT[(long)tid * REGS + row0 + 1] = prm[1][RK_ + N_ + tid];
  }
}

// ---------------- R5: parallel-prefix selective scan (coalesced inputs) ----
// block = (b,d) channel; thread = sequence position l (256 = 4 waves x 64).
__global__ __launch_bounds__(256) void k_scan(
    const float* __restrict__ deltaT, const float* __restrict__ uT,
    const float* __restrict__ zT, const float* __restrict__ BmT,
    const float* __restrict__ CmT, const float* __restrict__ alog,
    const float* __restrict__ Dp, float* __restrict__ ys){
  __shared__ float sAn[N_];
  __shared__ float sA[N_][4];
  __shared__ float sB[N_][4];
  int tid = threadIdx.x, lane = tid & 63, w = tid >> 6;
  int ch = blockIdx.x;
  int b = ch >> 9, d = ch & (DR_ - 1);
  if (tid < N_) sAn[tid] = -fminf(__expf(alog[d * N_ + tid]), 10000.f);
  long col = (long)b * R_ + tid;
  float dl = deltaT[(long)d * REGS + col];
  float uu = uT[(long)d * REGS + col];
  float zz = zT[(long)d * REGS + col];
  float Dd = Dp[d];
  float part = 0.f;
  __syncthreads();
  for (int nc = 0; nc < 6; ++nc){
    float bmv[8], cmv[8];
#pragma unroll
    for (int j = 0; j < 8; ++j){
      bmv[j] = BmT[(long)(nc * 8 + j) * REGS + col];
      cmv[j] = CmT[(long)(nc * 8 + j) * REGS + col];
    }
    float aA[8], aB[8];
#pragma unroll
    for (int j = 0; j < 8; ++j){
      int n = nc * 8 + j;
      float cc = fminf(fmaxf(dl * sAn[n], -30.f), 30.f);
      float a = exp2f(cc * 1.44269504f);
      float bv = dl * bmv[j] * uu;
#pragma unroll
      for (int s = 1; s < 64; s <<= 1){
        float a_sh = __shfl_up(a, (unsigned)s, 64);
        float b_sh = __shfl_up(bv, (unsigned)s, 64);
        float nb = fmaf(a, b_sh, bv);
        float na = a * a_sh;
        if (lane >= s){ bv = nb; a = na; }
      }
      aA[j] = a; aB[j] = bv;
      if (lane == 63){ sA[n][w] = a; sB[n][w] = bv; }
    }
    __syncthreads();
#pragma unroll
    for (int j = 0; j < 8; ++j){
      int n = nc * 8 + j;
      float hin = 0.f;
#pragma unroll
      for (int tt = 0; tt < 3; ++tt){
        if (tt < w) hin = sA[n][tt] * hin + sB[n][tt];
      }
      float h = fmaf(aA[j], hin, aB[j]);
      part = fmaf(cmv[j], h, part);
    }
    if (nc < 5) __syncthreads();
  }
  float yv = part + Dd * uu;
  float sz = zz / (1.f + __expf(-zz));
  ys[col * DR_ + d] = yv * sz;
}

// ---------------- R6: out_proj + residual + final LN + l2norm, 4 rows ------
__global__ __launch_bounds__(512) void k_out(
    const float* __restrict__ ys, const float* __restrict__ W,
    const float* __restrict__ region, const float* __restrict__ lnw,
    const float* __restrict__ lnb, float* __restrict__ outp,
    float* __restrict__ rt){
  __shared__ float yr[4][DR_];
  __shared__ float red[40];
  int tid = threadIdx.x;
  int r0 = blockIdx.x * 4;
  for (int i = tid; i < 4 * DR_; i += 512) yr[i >> 9][i & 511] = ys[(long)r0 * DR_ + i];
  __syncthreads();
  float y[4] = {0,0,0,0};
  for (int k = 0; k < DR_; ++k){
    float wv = W[k * DR_ + tid];
#pragma unroll
    for (int i = 0; i < 4; ++i) y[i] += yr[i][k] * wv;
  }
  float v[4], t4[4];
#pragma unroll
  for (int i = 0; i < 4; ++i){
    if (isnan(y[i])) y[i] = 0.f; else if (isinf(y[i])) y[i] = (y[i] > 0.f) ? 1.f : -1.f;
    v[i] = region[(long)(r0 + i) * DR_ + tid] + y[i];
    t4[i] = v[i];
  }
  block_sum4(t4, red);
  float dv[4];
#pragma unroll
  for (int i = 0; i < 4; ++i){ dv[i] = v[i] - t4[i] * (1.f / DR_); t4[i] = dv[i] * dv[i]; }
  block_sum4(t4, red);
  float o[4];
  float lw = lnw[tid], lb = lnb[tid];
#pragma unroll
  for (int i = 0; i < 4; ++i){
    o[i] = dv[i] * rsqrtf(t4[i] * (1.f / DR_) + 1e-5f) * lw + lb;
    outp[(long)(r0 + i) * DR_ + tid] = o[i];
    t4[i] = o[i] * o[i];
  }
  block_sum4(t4, red);
#pragma unroll
  for (int i = 0; i < 4; ++i)
    rt[(long)(r0 + i) * DR_ + tid] = o[i] / fmaxf(sqrtf(t4[i]), 1e-6f);
}

// ---------------- R7: similarity losses, 4 query rows per block ------------
__global__ __launch_bounds__(512) void k_loss(
    const float* __restrict__ rt, const int* __restrict__ nearm,
    const int* __restrict__ farm, float* __restrict__ accum){
  __shared__ __align__(16) float ar[4][DR_];
  __shared__ float ps[2][4][256];
  __shared__ float wsum[8][4];
  int blk = blockIdx.x, tid = threadIdx.x;
  int b = blk >> 6, q0 = (blk & 63) * 4;
  const float* rtb = rt + (long)b * R_ * DR_;
  for (int i = tid; i < 4 * DR_; i += 512) ar[i >> 9][i & 511] = rtb[(long)q0 * DR_ + i];
  __syncthreads();
  int s = tid & 255, h = tid >> 8;
  const float* rsrow = rtb + (long)s * DR_ + h * 256;
  float dq[4] = {0.f, 0.f, 0.f, 0.f};
  for (int k = 0; k < 256; k += 4){
    float4 yv = *(const float4*)(rsrow + k);
#pragma unroll
    for (int q = 0; q < 4; ++q){
      float4 x = *(const float4*)(&ar[q][h * 256 + k]);
      dq[q] += x.x * yv.x + x.y * yv.y + x.z * yv.z + x.w * yv.w;
    }
  }
#pragma unroll
  for (int q = 0; q < 4; ++q) ps[h][q][s] = dq[q];
  __syncthreads();
  float nl = 0.f, fl = 0.f, nc = 0.f, fc = 0.f;
  if (tid < 256){
#pragma unroll
    for (int q = 0; q < 4; ++q){
      float dot = ps[0][q][tid] + ps[1][q][tid];
      int nm = nearm[(q0 + q) * R_ + tid], fm = farm[(q0 + q) * R_ + tid];
      if (nm){ nl += 1.f - dot; if (b == 0) nc += 1.f; }
      if (fm){ fl += fmaxf(dot - 0.2f, 0.f); if (b == 0) fc += 1.f; }
    }
  }
  nl = wred_sum(nl); fl = wred_sum(fl); nc = wred_sum(nc); fc = wred_sum(fc);
  int w = tid >> 6, lane = tid & 63;
  if (lane == 0){ wsum[w][0] = nl; wsum[w][1] = fl; wsum[w][2] = nc; wsum[w][3] = fc; }
  __syncthreads();
  if (tid == 0){
    float a0 = 0, a1 = 0, a2 = 0, a3 = 0;
    for (int i = 0; i < 8; i++){ a0 += wsum[i][0]; a1 += wsum[i][1]; a2 += wsum[i][2]; a3 += wsum[i][3]; }
    atomicAdd(&accum[0], a0); atomicAdd(&accum[1], a1);
    if (b == 0){ atomicAdd(&accum[2], a2); atomicAdd(&accum[3], a3); }
  }
}

__global__ void k_final(const float* __restrict__ accum, float* __restrict__ outp){
  if (threadIdx.x == 0){
    float loss = accum[0] / fmaxf(accum[2], 1.f) + accum[1] / fmaxf(accum[3], 1.f);
    outp[REGS * DR_] = loss;
  }
}

extern "C" void kernel_launch(void* const* d_in, const int* in_sizes, int n_in,
                              void* d_out, int out_size, void* d_ws, size_t ws_size,
                              hipStream_t stream){
  const float* pt    = (const float*)d_in[0];
  const int*   pmask = (const int*)d_in[1];
  const int*   nearm = (const int*)d_in[2];
  const int*   farm  = (const int*)d_in[3];
  const float* lp    = (const float*)d_in[4];
  const float* glnw  = (const float*)d_in[5];
  const float* glnb  = (const float*)d_in[6];
  const float* gw1   = (const float*)d_in[7];
  const float* gb1   = (const float*)d_in[8];
  const float* gw2   = (const float*)d_in[9];
  const float* pln1w = (const float*)d_in[11];
  const float* pln1b = (const float*)d_in[12];
  const float* pw1   = (const float*)d_in[13];
  const float* pb1   = (const float*)d_in[14];
  const float* pw2   = (const float*)d_in[15];
  const float* pb2   = (const float*)d_in[16];
  const float* pln2w = (const float*)d_in[17];
  const float* pln2b = (const float*)d_in[18];
  const float* inpw  = (const float*)d_in[19];
  const float* xpw   = (const float*)d_in[20];
  const float* dtw   = (const float*)d_in[21];
  const float* dtb   = (const float*)d_in[22];
  const float* alog  = (const float*)d_in[23];
  const float* dpar  = (const float*)d_in[24];
  const float* opw   = (const float*)d_in[25];
  const float* slnw  = (const float*)d_in[26];
  const float* slnb  = (const float*)d_in[27];

  char* ws = (char*)d_ws;
  size_t off = 0;
  auto alloc = [&](size_t bytes){ size_t o = off; off += (bytes + 255) & ~(size_t)255; return o; };
  ushort_t* W1pT = (ushort_t*)(ws + alloc((size_t)DR_ * DP_ * 2));
  float* s1     = (float*)(ws + alloc(DR_ * 4));
  float* b1p    = (float*)(ws + alloc(DR_ * 4));
  float* pooled = (float*)(ws + alloc((size_t)REGS * DP_ * 4));
  float* region = (float*)(ws + alloc((size_t)REGS * DR_ * 4));
  float* u      = (float*)(ws + alloc((size_t)REGS * DR_ * 4));
  float* uT     = (float*)(ws + alloc((size_t)REGS * DR_ * 4));
  float* zT     = (float*)(ws + alloc((size_t)REGS * DR_ * 4));
  float* deltaT = (float*)(ws + alloc((size_t)REGS * DR_ * 4));
  float* BmT    = (float*)(ws + alloc((size_t)REGS * N_ * 4));
  float* CmT    = (float*)(ws + alloc((size_t)REGS * N_ * 4));
  float* ys     = (float*)(ws + alloc((size_t)REGS * DR_ * 4));
  float* rt     = (float*)(ws + alloc((size_t)REGS * DR_ * 4));
  float* accum  = (float*)(ws + alloc(4 * 4));

  float* outp = (float*)d_out;

  k_prep<<<dim3(8), dim3(64), 0, stream>>>(gw1, glnw, glnb, gb1, W1pT, s1, b1p, accum);
  k_gate_pool<<<dim3(REGS), dim3(512), 0, stream>>>(pt, lp, W1pT, s1, b1p, gw2, pmask, pooled);
  k_region_mlp<<<dim3(REGS / 4), dim3(512), 0, stream>>>(pooled, pln1w, pln1b, pw1, pb1, pw2, pb2, pln2w, pln2b, region);
  k_inproj<<<dim3(REGS / 4), dim3(512), 0, stream>>>(region, inpw, u, uT, zT);
  k_xproj<<<dim3(REGS / 2), dim3(512), 0, stream>>>(u, xpw, dtw, dtb, deltaT, BmT, CmT);
  k_scan<<<dim3(B_ * DR_), dim3(256), 0, stream>>>(deltaT, uT, zT, BmT, CmT, alog, dpar, ys);
  k_out<<<dim3(REGS / 4), dim3(512), 0, stream>>>(ys, opw, region, slnw, slnb, outp, rt);
  k_loss<<<dim3(REGS / 4), dim3(512), 0, stream>>>(rt, nearm, farm, accum);
  k_final<<<dim3(1), dim3(64), 0, stream>>>(accum, outp);
}

// Round 5
// 355.031 us; speedup vs baseline: 1.8165x; 1.1076x over previous
//
#include <hip/hip_runtime.h>
#include <hip/hip_bf16.h>
#include <math.h>

#define B_ 4
#define R_ 256
#define P_ 64
#define DP_ 384
#define DR_ 512
#define N_ 48
#define RK_ 24
#define MROWS (B_*R_*P_)   /* 65536 */
#define REGS  (B_*R_)      /* 1024  */

typedef unsigned short ushort_t;
typedef __attribute__((ext_vector_type(8))) short bf16x8;
typedef __attribute__((ext_vector_type(4))) float f32x4;

#define GLOAD16(g, l) __builtin_amdgcn_global_load_lds( \
    (const __attribute__((address_space(1))) unsigned int*)(g), \
    (__attribute__((address_space(3))) unsigned int*)(l), 16, 0, 0)

__device__ __forceinline__ float us2f(unsigned short u){
  union { unsigned int i; float f; } x; x.i = ((unsigned int)u) << 16; return x.f;
}
__device__ __forceinline__ unsigned short f2us(float f){
  __hip_bfloat16 h = __float2bfloat16(f);
  return *reinterpret_cast<unsigned short*>(&h);
}
__device__ __forceinline__ float gelu_f(float x){
  return 0.5f * x * (1.0f + erff(x * 0.70710678118654752f));
}
__device__ __forceinline__ float wred_sum(float v){
#pragma unroll
  for (int m = 1; m < 64; m <<= 1) v += __shfl_xor(v, m, 64);
  return v;
}
// 4 simultaneous block-wide sums (512-thread blocks); s >= 40 floats
__device__ __forceinline__ void block_sum4(float v[4], float* s){
  int lane = threadIdx.x & 63, wid = threadIdx.x >> 6;
#pragma unroll
  for (int i = 0; i < 4; ++i){
    float x = v[i];
#pragma unroll
    for (int m = 1; m < 64; m <<= 1) x += __shfl_xor(x, m, 64);
    if (lane == 0) s[wid * 4 + i] = x;
  }
  __syncthreads();
  if (threadIdx.x < 4){
    float t = 0.f;
    for (int t2 = 0; t2 < 8; ++t2) t += s[t2 * 4 + threadIdx.x];
    s[32 + threadIdx.x] = t;
  }
  __syncthreads();
#pragma unroll
  for (int i = 0; i < 4; ++i) v[i] = s[32 + i];
  __syncthreads();
}

// ---------------- C0: weight prep, parallel. 8 blocks x 512 ----------------
// block = 64 n-cols; thread (seg=tid>>6, nl=tid&63) covers 48 k for one n.
__global__ __launch_bounds__(512) void k_prep(
    const float* __restrict__ gw1, const float* __restrict__ glnw,
    const float* __restrict__ glnb, const float* __restrict__ gb1,
    ushort_t* __restrict__ W1pT, float* __restrict__ s1,
    float* __restrict__ b1p, float* __restrict__ accum){
  __shared__ float pss[8][64], psb[8][64];
  int tid = threadIdx.x, seg = tid >> 6, nl = tid & 63;
  int n = blockIdx.x * 64 + nl;
  if (blockIdx.x == 0 && tid < 4) accum[tid] = 0.f;
  float s = 0.f, sb = 0.f;
  int k0 = seg * 48;
  for (int i = 0; i < 48; ++i){
    int k = k0 + i;
    float w1 = gw1[k * DR_ + n];
    float v = glnw[k] * w1;
    unsigned short vr = f2us(v);
    s  += us2f(vr);
    sb += glnb[k] * w1;
    W1pT[(size_t)n * DP_ + k] = vr;
  }
  pss[seg][nl] = s; psb[seg][nl] = sb;
  __syncthreads();
  if (tid < 64){
    float ts = 0.f, tb = 0.f;
    for (int j = 0; j < 8; ++j){ ts += pss[j][tid]; tb += psb[j][tid]; }
    s1[blockIdx.x * 64 + tid] = ts;
    b1p[blockIdx.x * 64 + tid] = gb1[blockIdx.x * 64 + tid] + tb;
  }
}

// ---------------- S0: xb = bf16(pt + lp) + LN stats. 8 rows/block ----------
__global__ __launch_bounds__(512) void k_xform(
    const float* __restrict__ pt, const float* __restrict__ lp,
    ushort_t* __restrict__ xb, float* __restrict__ mu, float* __restrict__ rsg){
  int tid = threadIdx.x, w = tid >> 6, lane = tid & 63;
  size_t r = (size_t)blockIdx.x * 8 + w;
  int p = (int)(r & (P_ - 1));
  const float* xr = pt + r * DP_ + lane * 6;
  const float* lr = lp + (size_t)p * DP_ + lane * 6;
  float x[6];
  float s = 0.f, ss = 0.f;
#pragma unroll
  for (int i = 0; i < 6; i += 2){
    float2 a = *(const float2*)(xr + i);
    float2 b = *(const float2*)(lr + i);
    x[i] = a.x + b.x; x[i + 1] = a.y + b.y;
  }
#pragma unroll
  for (int i = 0; i < 6; ++i){ s += x[i]; ss += x[i] * x[i]; }
  s = wred_sum(s); ss = wred_sum(ss);
  if (lane == 0){
    float m = s * (1.f / DP_);
    float var = ss * (1.f / DP_) - m * m;
    mu[r] = m;
    rsg[r] = rsqrtf(var + 1e-5f);
  }
  ushort_t* xw = xb + r * DP_ + lane * 6;
#pragma unroll
  for (int i = 0; i < 6; i += 2){
    ushort2 u2; u2.x = f2us(x[i]); u2.y = f2us(x[i + 1]);
    *(ushort2*)(xw + i) = u2;
  }
}

// ---- P2 fused: gate GEMM (xb bf16 via global_load_lds; B direct from L2)
//      + folded LN + gelu + logit + softmax + attention pooling.
__global__ __launch_bounds__(512, 4) void k_gate_pool(
    const ushort_t* __restrict__ xb,   // (65536 x 384) bf16
    const ushort_t* __restrict__ BT,   // W1pT (512 x 384) bf16
    const float* __restrict__ mu, const float* __restrict__ rsg,
    const float* __restrict__ s1, const float* __restrict__ b1p,
    const float* __restrict__ w2, const int* __restrict__ pmask,
    float* __restrict__ pooled){
  __shared__ __align__(16) ushort_t Abuf[64 * 64];   // 8 KB, swizzled chunks
  __shared__ float logit_lds[64];
  __shared__ float smu[64], srs[64];
  __shared__ float attn[64];
  int tid = threadIdx.x;
  int lane = tid & 63, w = tid >> 6;
  int t = lane & 15, g = lane >> 4;
  long r0 = (long)blockIdx.x * 64;
  if (tid < 64){
    logit_lds[tid] = 0.f;
    smu[tid] = mu[r0 + tid];
    srs[tid] = rsg[r0 + tid];
  }

  f32x4 acc[4][4];
#pragma unroll
  for (int m = 0; m < 4; ++m)
#pragma unroll
    for (int n = 0; n < 4; ++n) acc[m][n] = (f32x4){0.f, 0.f, 0.f, 0.f};

  // per-lane staging source (pre-swizzled): wave w stages rows w*8..w*8+7
  int arow8 = (w << 3) + (lane >> 3);
  int akc = lane & 7;
  const ushort_t* asrc0 = xb + (size_t)(r0 + arow8) * DP_ + ((akc ^ (arow8 & 7)) << 3);
  ushort_t* adst = Abuf + (w << 9);   // wave-uniform base; HW adds lane*16B

  for (int kt = 0; kt < 6; ++kt){
    __syncthreads();                  // previous compute done before overwrite
    GLOAD16(asrc0 + kt * 64, adst);
    __syncthreads();                  // drain: stage complete
#pragma unroll
    for (int kk = 0; kk < 2; ++kk){
      int ch = kk * 4 + g;
      bf16x8 af[4], bfr[4];
#pragma unroll
      for (int m = 0; m < 4; ++m){
        int row = m * 16 + t;
        af[m] = *(const bf16x8*)(Abuf + row * 64 + ((ch ^ (row & 7)) << 3));
      }
#pragma unroll
      for (int n = 0; n < 4; ++n){
        int rowb = w * 64 + n * 16 + t;
        bfr[n] = *(const bf16x8*)(BT + (size_t)rowb * DP_ + kt * 64 + ch * 8);
      }
#pragma unroll
      for (int m = 0; m < 4; ++m)
#pragma unroll
        for (int n = 0; n < 4; ++n)
          acc[m][n] = __builtin_amdgcn_mfma_f32_16x16x32_bf16(af[m], bfr[n], acc[m][n], 0, 0, 0);
    }
  }
  __syncthreads();

  // epilogue: folded LN + gelu + reduce against gate_w2
  float w2c[4], s1c[4], b1c[4];
#pragma unroll
  for (int n = 0; n < 4; ++n){
    int c = w * 64 + n * 16 + t;
    w2c[n] = w2[c]; s1c[n] = s1[c]; b1c[n] = b1p[c];
  }
#pragma unroll
  for (int m = 0; m < 4; ++m){
#pragma unroll
    for (int j = 0; j < 4; ++j){
      int rl = m * 16 + g * 4 + j;
      float mur = smu[rl], rs = srs[rl];
      float part = 0.f;
#pragma unroll
      for (int n = 0; n < 4; ++n){
        float gp = rs * acc[m][n][j] - mur * rs * s1c[n] + b1c[n];
        part += gelu_f(gp) * w2c[n];
      }
#pragma unroll
      for (int msk = 1; msk < 16; msk <<= 1) part += __shfl_xor(part, msk, 64);
      if (t == 0) atomicAdd(&logit_lds[rl], part);
    }
  }
  __syncthreads();

  // masked softmax over the 64 patches (gate_b2 cancels in softmax)
  if (tid < 64){
    int mk = pmask[r0 + tid];
    float lv = logit_lds[tid];
    float lm = mk ? lv : -3.4e38f;
    float M = lm;
#pragma unroll
    for (int m2 = 1; m2 < 64; m2 <<= 1) M = fmaxf(M, __shfl_xor(M, m2, 64));
    float e = mk ? __expf(lv - M) : 0.f;
    float S = e;
#pragma unroll
    for (int m2 = 1; m2 < 64; m2 <<= 1) S += __shfl_xor(S, m2, 64);
    float a = (S > 0.f) ? e / S : 0.f;
    float S2 = a;
#pragma unroll
    for (int m2 = 1; m2 < 64; m2 <<= 1) S2 += __shfl_xor(S2, m2, 64);
    attn[tid] = a / fmaxf(S2, 1e-6f);
  }
  __syncthreads();

  // attention pooling from xb (L2/L3-hot)
  if (tid < DP_){
    float accp = 0.f;
#pragma unroll 4
    for (int p = 0; p < P_; ++p)
      accp += attn[p] * us2f(xb[(size_t)(r0 + p) * DP_ + tid]);
    pooled[(long)blockIdx.x * DP_ + tid] = accp;
  }
}

// ---------------- R1+R3+R4 fused: region MLP -> in_proj -> x_proj ----------
__global__ __launch_bounds__(512) void k_region(
    const float* __restrict__ pooled,
    const float* __restrict__ ln1w, const float* __restrict__ ln1b,
    const float* __restrict__ pw1, const float* __restrict__ pb1,
    const float* __restrict__ pw2, const float* __restrict__ pb2,
    const float* __restrict__ ln2w, const float* __restrict__ ln2b,
    const float* __restrict__ inpw, const float* __restrict__ xpw,
    const float* __restrict__ dtw, const float* __restrict__ dtb,
    float* __restrict__ region, float* __restrict__ uT, float* __restrict__ zT,
    float* __restrict__ deltaT, float* __restrict__ BmT, float* __restrict__ CmT){
  __shared__ float xr[4][DP_];
  __shared__ float p1[4][DR_];
  __shared__ float rg[4][DR_];
  __shared__ float us[4][DR_];
  __shared__ float ps[4][4][128];
  __shared__ float prm[4][RK_ + 2 * N_];
  __shared__ float red[40];
  int tid = threadIdx.x;
  int r0 = blockIdx.x * 4;
  for (int i = tid; i < 4 * DP_; i += 512) xr[i / DP_][i % DP_] = pooled[(long)r0 * DP_ + i];
  __syncthreads();
  float v[4], t4[4];
#pragma unroll
  for (int i = 0; i < 4; ++i){ v[i] = (tid < DP_) ? xr[i][tid] : 0.f; t4[i] = v[i]; }
  block_sum4(t4, red);
  float dv[4];
#pragma unroll
  for (int i = 0; i < 4; ++i){ dv[i] = (tid < DP_) ? (v[i] - t4[i] * (1.f / DP_)) : 0.f; t4[i] = dv[i] * dv[i]; }
  block_sum4(t4, red);
  float lw = (tid < DP_) ? ln1w[tid] : 0.f, lb = (tid < DP_) ? ln1b[tid] : 0.f;
  if (tid < DP_){
#pragma unroll
    for (int i = 0; i < 4; ++i)
      xr[i][tid] = dv[i] * rsqrtf(t4[i] * (1.f / DP_) + 1e-5f) * lw + lb;
  }
  __syncthreads();
  float a[4];
  float pb = pb1[tid];
#pragma unroll
  for (int i = 0; i < 4; ++i) a[i] = pb;
  for (int k = 0; k < DP_; ++k){
    float wv = pw1[k * DR_ + tid];
#pragma unroll
    for (int i = 0; i < 4; ++i) a[i] += xr[i][k] * wv;
  }
#pragma unroll
  for (int i = 0; i < 4; ++i) p1[i][tid] = gelu_f(a[i]);
  __syncthreads();
  float q[4];
  float pbb = pb2[tid];
#pragma unroll
  for (int i = 0; i < 4; ++i) q[i] = pbb;
  for (int k = 0; k < DR_; ++k){
    float wv = pw2[k * DR_ + tid];
#pragma unroll
    for (int i = 0; i < 4; ++i) q[i] += p1[i][k] * wv;
  }
#pragma unroll
  for (int i = 0; i < 4; ++i) t4[i] = q[i];
  block_sum4(t4, red);
  float d2[4];
#pragma unroll
  for (int i = 0; i < 4; ++i){ d2[i] = q[i] - t4[i] * (1.f / DR_); t4[i] = d2[i] * d2[i]; }
  block_sum4(t4, red);
  float o[4];
  float l2w = ln2w[tid], l2b = ln2b[tid];
#pragma unroll
  for (int i = 0; i < 4; ++i){
    o[i] = d2[i] * rsqrtf(t4[i] * (1.f / DR_) + 1e-5f) * l2w + l2b;
    if (isnan(o[i])) o[i] = 0.f; else if (isinf(o[i])) o[i] = (o[i] > 0.f) ? 1.f : -1.f;
    t4[i] = o[i] * o[i];
  }
  block_sum4(t4, red);
#pragma unroll
  for (int i = 0; i < 4; ++i){
    float rv = o[i] / fmaxf(sqrtf(t4[i]), 1e-6f);
    rg[i][tid] = rv;
    region[(long)(r0 + i) * DR_ + tid] = rv;
  }
  __syncthreads();
  // in_proj: u,z (thread cols tid and tid+512)
  float ua[4] = {0,0,0,0}, zb[4] = {0,0,0,0};
  for (int k = 0; k < DR_; ++k){
    float w1 = inpw[k * 1024 + tid];
    float w2v = inpw[k * 1024 + tid + 512];
#pragma unroll
    for (int i = 0; i < 4; ++i){ float x = rg[i][k]; ua[i] += x * w1; zb[i] += x * w2v; }
  }
#pragma unroll
  for (int i = 0; i < 4; ++i){
    us[i][tid] = ua[i];
    uT[(long)tid * REGS + r0 + i] = ua[i];
    zT[(long)tid * REGS + r0 + i] = zb[i];
  }
  __syncthreads();
  // x_proj: K-split (4 segs x 128), 120 out cols, 4 rows
  int sseg = tid >> 7, c = tid & 127;
  float pr[4] = {0,0,0,0};
  if (c < RK_ + 2 * N_){
    int kb = sseg * 128;
    for (int k = kb; k < kb + 128; ++k){
      float wv = xpw[k * (RK_ + 2 * N_) + c];
#pragma unroll
      for (int i = 0; i < 4; ++i) pr[i] += us[i][k] * wv;
    }
  }
#pragma unroll
  for (int i = 0; i < 4; ++i) ps[sseg][i][c] = pr[i];
  __syncthreads();
  if (tid < 256){
    int rr2 = tid >> 7, cc = tid & 127;
    if (cc < RK_ + 2 * N_){
      prm[rr2][cc] = ps[0][rr2][cc] + ps[1][rr2][cc] + ps[2][rr2][cc] + ps[3][rr2][cc];
      prm[rr2 + 2][cc] = ps[0][rr2 + 2][cc] + ps[1][rr2 + 2][cc] + ps[2][rr2 + 2][cc] + ps[3][rr2 + 2][cc];
    }
  }
  __syncthreads();
  // dt head -> delta (transposed)
#pragma unroll
  for (int r = 0; r < 4; ++r){
    float aa = dtb[tid];
#pragma unroll
    for (int j = 0; j < RK_; ++j) aa += prm[r][j] * dtw[j * DR_ + tid];
    float sp = (aa > 20.f) ? aa : log1pf(expf(aa));
    deltaT[(long)tid * REGS + r0 + r] = fminf(sp, 10.f);
  }
  if (tid < N_){
#pragma unroll
    for (int r = 0; r < 4; ++r){
      BmT[(long)tid * REGS + r0 + r] = prm[r][RK_ + tid];
      CmT[(long)tid * REGS + r0 + r] = prm[r][RK_ + N_ + tid];
    }
  }
}

// ---------------- R5: parallel-prefix selective scan (coalesced inputs) ----
__global__ __launch_bounds__(256) void k_scan(
    const float* __restrict__ deltaT, const float* __restrict__ uT,
    const float* __restrict__ zT, const float* __restrict__ BmT,
    const float* __restrict__ CmT, const float* __restrict__ alog,
    const float* __restrict__ Dp, float* __restrict__ ys){
  __shared__ float sAn[N_];
  __shared__ float sA[N_][4];
  __shared__ float sB[N_][4];
  int tid = threadIdx.x, lane = tid & 63, w = tid >> 6;
  int ch = blockIdx.x;
  int b = ch >> 9, d = ch & (DR_ - 1);
  if (tid < N_) sAn[tid] = -fminf(__expf(alog[d * N_ + tid]), 10000.f);
  long col = (long)b * R_ + tid;
  float dl = deltaT[(long)d * REGS + col];
  float uu = uT[(long)d * REGS + col];
  float zz = zT[(long)d * REGS + col];
  float Dd = Dp[d];
  float part = 0.f;
  __syncthreads();
  for (int nc = 0; nc < 6; ++nc){
    float bmv[8], cmv[8];
#pragma unroll
    for (int j = 0; j < 8; ++j){
      bmv[j] = BmT[(long)(nc * 8 + j) * REGS + col];
      cmv[j] = CmT[(long)(nc * 8 + j) * REGS + col];
    }
    float aA[8], aB[8];
#pragma unroll
    for (int j = 0; j < 8; ++j){
      int n = nc * 8 + j;
      float cc = fminf(fmaxf(dl * sAn[n], -30.f), 30.f);
      float a = exp2f(cc * 1.44269504f);
      float bv = dl * bmv[j] * uu;
#pragma unroll
      for (int s = 1; s < 64; s <<= 1){
        float a_sh = __shfl_up(a, (unsigned)s, 64);
        float b_sh = __shfl_up(bv, (unsigned)s, 64);
        float nb = fmaf(a, b_sh, bv);
        float na = a * a_sh;
        if (lane >= s){ bv = nb; a = na; }
      }
      aA[j] = a; aB[j] = bv;
      if (lane == 63){ sA[n][w] = a; sB[n][w] = bv; }
    }
    __syncthreads();
#pragma unroll
    for (int j = 0; j < 8; ++j){
      int n = nc * 8 + j;
      float hin = 0.f;
#pragma unroll
      for (int tt = 0; tt < 3; ++tt){
        if (tt < w) hin = sA[n][tt] * hin + sB[n][tt];
      }
      float h = fmaf(aA[j], hin, aB[j]);
      part = fmaf(cmv[j], h, part);
    }
    if (nc < 5) __syncthreads();
  }
  float yv = part + Dd * uu;
  float sz = zz / (1.f + __expf(-zz));
  ys[col * DR_ + d] = yv * sz;
}

// ---------------- R6: out_proj + residual + final LN + l2norm, 4 rows ------
__global__ __launch_bounds__(512) void k_out(
    const float* __restrict__ ys, const float* __restrict__ W,
    const float* __restrict__ region, const float* __restrict__ lnw,
    const float* __restrict__ lnb, float* __restrict__ outp,
    float* __restrict__ rt){
  __shared__ float yr[4][DR_];
  __shared__ float red[40];
  int tid = threadIdx.x;
  int r0 = blockIdx.x * 4;
  for (int i = tid; i < 4 * DR_; i += 512) yr[i >> 9][i & 511] = ys[(long)r0 * DR_ + i];
  __syncthreads();
  float y[4] = {0,0,0,0};
  for (int k = 0; k < DR_; ++k){
    float wv = W[k * DR_ + tid];
#pragma unroll
    for (int i = 0; i < 4; ++i) y[i] += yr[i][k] * wv;
  }
  float v[4], t4[4];
#pragma unroll
  for (int i = 0; i < 4; ++i){
    if (isnan(y[i])) y[i] = 0.f; else if (isinf(y[i])) y[i] = (y[i] > 0.f) ? 1.f : -1.f;
    v[i] = region[(long)(r0 + i) * DR_ + tid] + y[i];
    t4[i] = v[i];
  }
  block_sum4(t4, red);
  float dv[4];
#pragma unroll
  for (int i = 0; i < 4; ++i){ dv[i] = v[i] - t4[i] * (1.f / DR_); t4[i] = dv[i] * dv[i]; }
  block_sum4(t4, red);
  float o[4];
  float lw = lnw[tid], lb = lnb[tid];
#pragma unroll
  for (int i = 0; i < 4; ++i){
    o[i] = dv[i] * rsqrtf(t4[i] * (1.f / DR_) + 1e-5f) * lw + lb;
    outp[(long)(r0 + i) * DR_ + tid] = o[i];
    t4[i] = o[i] * o[i];
  }
  block_sum4(t4, red);
#pragma unroll
  for (int i = 0; i < 4; ++i)
    rt[(long)(r0 + i) * DR_ + tid] = o[i] / fmaxf(sqrtf(t4[i]), 1e-6f);
}

// ---------------- R7: similarity losses, 4 query rows per block ------------
__global__ __launch_bounds__(512) void k_loss(
    const float* __restrict__ rt, const int* __restrict__ nearm,
    const int* __restrict__ farm, float* __restrict__ accum){
  __shared__ __align__(16) float ar[4][DR_];
  __shared__ float ps[2][4][256];
  __shared__ float wsum[8][4];
  int blk = blockIdx.x, tid = threadIdx.x;
  int b = blk >> 6, q0 = (blk & 63) * 4;
  const float* rtb = rt + (long)b * R_ * DR_;
  for (int i = tid; i < 4 * DR_; i += 512) ar[i >> 9][i & 511] = rtb[(long)q0 * DR_ + i];
  __syncthreads();
  int s = tid & 255, h = tid >> 8;
  const float* rsrow = rtb + (long)s * DR_ + h * 256;
  float dq[4] = {0.f, 0.f, 0.f, 0.f};
  for (int k = 0; k < 256; k += 4){
    float4 yv = *(const float4*)(rsrow + k);
#pragma unroll
    for (int q = 0; q < 4; ++q){
      float4 x = *(const float4*)(&ar[q][h * 256 + k]);
      dq[q] += x.x * yv.x + x.y * yv.y + x.z * yv.z + x.w * yv.w;
    }
  }
#pragma unroll
  for (int q = 0; q < 4; ++q) ps[h][q][s] = dq[q];
  __syncthreads();
  float nl = 0.f, fl = 0.f, nc = 0.f, fc = 0.f;
  if (tid < 256){
#pragma unroll
    for (int q = 0; q < 4; ++q){
      float dot = ps[0][q][tid] + ps[1][q][tid];
      int nm = nearm[(q0 + q) * R_ + tid], fm = farm[(q0 + q) * R_ + tid];
      if (nm){ nl += 1.f - dot; if (b == 0) nc += 1.f; }
      if (fm){ fl += fmaxf(dot - 0.2f, 0.f); if (b == 0) fc += 1.f; }
    }
  }
  nl = wred_sum(nl); fl = wred_sum(fl); nc = wred_sum(nc); fc = wred_sum(fc);
  int w = tid >> 6, lane = tid & 63;
  if (lane == 0){ wsum[w][0] = nl; wsum[w][1] = fl; wsum[w][2] = nc; wsum[w][3] = fc; }
  __syncthreads();
  if (tid == 0){
    float a0 = 0, a1 = 0, a2 = 0, a3 = 0;
    for (int i = 0; i < 8; i++){ a0 += wsum[i][0]; a1 += wsum[i][1]; a2 += wsum[i][2]; a3 += wsum[i][3]; }
    atomicAdd(&accum[0], a0); atomicAdd(&accum[1], a1);
    if (b == 0){ atomicAdd(&accum[2], a2); atomicAdd(&accum[3], a3); }
  }
}

__global__ void k_final(const float* __restrict__ accum, float* __restrict__ outp){
  if (threadIdx.x == 0){
    float loss = accum[0] / fmaxf(accum[2], 1.f) + accum[1] / fmaxf(accum[3], 1.f);
    outp[REGS * DR_] = loss;
  }
}

extern "C" void kernel_launch(void* const* d_in, const int* in_sizes, int n_in,
                              void* d_out, int out_size, void* d_ws, size_t ws_size,
                              hipStream_t stream){
  const float* pt    = (const float*)d_in[0];
  const int*   pmask = (const int*)d_in[1];
  const int*   nearm = (const int*)d_in[2];
  const int*   farm  = (const int*)d_in[3];
  const float* lp    = (const float*)d_in[4];
  const float* glnw  = (const float*)d_in[5];
  const float* glnb  = (const float*)d_in[6];
  const float* gw1   = (const float*)d_in[7];
  const float* gb1   = (const float*)d_in[8];
  const float* gw2   = (const float*)d_in[9];
  const float* pln1w = (const float*)d_in[11];
  const float* pln1b = (const float*)d_in[12];
  const float* pw1   = (const float*)d_in[13];
  const float* pb1   = (const float*)d_in[14];
  const float* pw2   = (const float*)d_in[15];
  const float* pb2   = (const float*)d_in[16];
  const float* pln2w = (const float*)d_in[17];
  const float* pln2b = (const float*)d_in[18];
  const float* inpw  = (const float*)d_in[19];
  const float* xpw   = (const float*)d_in[20];
  const float* dtw   = (const float*)d_in[21];
  const float* dtb   = (const float*)d_in[22];
  const float* alog  = (const float*)d_in[23];
  const float* dpar  = (const float*)d_in[24];
  const float* opw   = (const float*)d_in[25];
  const float* slnw  = (const float*)d_in[26];
  const float* slnb  = (const float*)d_in[27];

  char* ws = (char*)d_ws;
  size_t off = 0;
  auto alloc = [&](size_t bytes){ size_t o = off; off += (bytes + 255) & ~(size_t)255; return o; };
  ushort_t* W1pT = (ushort_t*)(ws + alloc((size_t)DR_ * DP_ * 2));
  float* s1     = (float*)(ws + alloc(DR_ * 4));
  float* b1p    = (float*)(ws + alloc(DR_ * 4));
  ushort_t* xb  = (ushort_t*)(ws + alloc((size_t)MROWS * DP_ * 2));
  float* mu     = (float*)(ws + alloc((size_t)MROWS * 4));
  float* rsg    = (float*)(ws + alloc((size_t)MROWS * 4));
  float* pooled = (float*)(ws + alloc((size_t)REGS * DP_ * 4));
  float* region = (float*)(ws + alloc((size_t)REGS * DR_ * 4));
  float* uT     = (float*)(ws + alloc((size_t)REGS * DR_ * 4));
  float* zT     = (float*)(ws + alloc((size_t)REGS * DR_ * 4));
  float* deltaT = (float*)(ws + alloc((size_t)REGS * DR_ * 4));
  float* BmT    = (float*)(ws + alloc((size_t)REGS * N_ * 4));
  float* CmT    = (float*)(ws + alloc((size_t)REGS * N_ * 4));
  float* ys     = (float*)(ws + alloc((size_t)REGS * DR_ * 4));
  float* rt     = (float*)(ws + alloc((size_t)REGS * DR_ * 4));
  float* accum  = (float*)(ws + alloc(4 * 4));

  float* outp = (float*)d_out;

  k_prep<<<dim3(8), dim3(512), 0, stream>>>(gw1, glnw, glnb, gb1, W1pT, s1, b1p, accum);
  k_xform<<<dim3(MROWS / 8), dim3(512), 0, stream>>>(pt, lp, xb, mu, rsg);
  k_gate_pool<<<dim3(REGS), dim3(512), 0, stream>>>(xb, W1pT, mu, rsg, s1, b1p, gw2, pmask, pooled);
  k_region<<<dim3(REGS / 4), dim3(512), 0, stream>>>(pooled, pln1w, pln1b, pw1, pb1, pw2, pb2, pln2w, pln2b,
                                                     inpw, xpw, dtw, dtb, region, uT, zT, deltaT, BmT, CmT);
  k_scan<<<dim3(B_ * DR_), dim3(256), 0, stream>>>(deltaT, uT, zT, BmT, CmT, alog, dpar, ys);
  k_out<<<dim3(REGS / 4), dim3(512), 0, stream>>>(ys, opw, region, slnw, slnb, outp, rt);
  k_loss<<<dim3(REGS / 4), dim3(512), 0, stream>>>(rt, nearm, farm, accum);
  k_final<<<dim3(1), dim3(64), 0, stream>>>(accum, outp);
}

// Round 6
// 330.418 us; speedup vs baseline: 1.9518x; 1.0745x over previous
//
#include <hip/hip_runtime.h>
#include <hip/hip_bf16.h>
#include <math.h>

#define B_ 4
#define R_ 256
#define P_ 64
#define DP_ 384
#define DR_ 512
#define N_ 48
#define RK_ 24
#define MROWS (B_*R_*P_)   /* 65536 */
#define REGS  (B_*R_)      /* 1024  */

typedef unsigned short ushort_t;
typedef __attribute__((ext_vector_type(8))) short bf16x8;
typedef __attribute__((ext_vector_type(4))) float f32x4;

#define GLOAD16(g, l) __builtin_amdgcn_global_load_lds( \
    (const __attribute__((address_space(1))) unsigned int*)(g), \
    (__attribute__((address_space(3))) unsigned int*)(l), 16, 0, 0)

__device__ __forceinline__ float us2f(unsigned short u){
  union { unsigned int i; float f; } x; x.i = ((unsigned int)u) << 16; return x.f;
}
__device__ __forceinline__ unsigned short f2us(float f){
  __hip_bfloat16 h = __float2bfloat16(f);
  return *reinterpret_cast<unsigned short*>(&h);
}
__device__ __forceinline__ float gelu_f(float x){
  return 0.5f * x * (1.0f + erff(x * 0.70710678118654752f));
}
__device__ __forceinline__ float wred_sum(float v){
#pragma unroll
  for (int m = 1; m < 64; m <<= 1) v += __shfl_xor(v, m, 64);
  return v;
}
// 4 simultaneous block-wide sums (512-thread blocks); s >= 40 floats
__device__ __forceinline__ void block_sum4(float v[4], float* s){
  int lane = threadIdx.x & 63, wid = threadIdx.x >> 6;
#pragma unroll
  for (int i = 0; i < 4; ++i){
    float x = v[i];
#pragma unroll
    for (int m = 1; m < 64; m <<= 1) x += __shfl_xor(x, m, 64);
    if (lane == 0) s[wid * 4 + i] = x;
  }
  __syncthreads();
  if (threadIdx.x < 4){
    float t = 0.f;
    for (int t2 = 0; t2 < 8; ++t2) t += s[t2 * 4 + threadIdx.x];
    s[32 + threadIdx.x] = t;
  }
  __syncthreads();
#pragma unroll
  for (int i = 0; i < 4; ++i) v[i] = s[32 + i];
  __syncthreads();
}
// 2 simultaneous block-wide sums (512-thread blocks); s >= 18 floats
__device__ __forceinline__ void block_sum2(float& a, float& b, float* s){
  int lane = threadIdx.x & 63, wid = threadIdx.x >> 6;
  float x = a, y = b;
#pragma unroll
  for (int m = 1; m < 64; m <<= 1){ x += __shfl_xor(x, m, 64); y += __shfl_xor(y, m, 64); }
  if (lane == 0){ s[wid * 2] = x; s[wid * 2 + 1] = y; }
  __syncthreads();
  if (threadIdx.x < 2){
    float t = 0.f;
    for (int j = 0; j < 8; ++j) t += s[j * 2 + threadIdx.x];
    s[16 + threadIdx.x] = t;
  }
  __syncthreads();
  a = s[16]; b = s[17];
  __syncthreads();
}

// ---------------- C0: weight prep, parallel. 8 blocks x 512 ----------------
__global__ __launch_bounds__(512) void k_prep(
    const float* __restrict__ gw1, const float* __restrict__ glnw,
    const float* __restrict__ glnb, const float* __restrict__ gb1,
    ushort_t* __restrict__ W1pT, float* __restrict__ s1,
    float* __restrict__ b1p, float* __restrict__ accum){
  __shared__ float pss[8][64], psb[8][64];
  int tid = threadIdx.x, seg = tid >> 6, nl = tid & 63;
  int n = blockIdx.x * 64 + nl;
  if (blockIdx.x == 0 && tid < 4) accum[tid] = 0.f;
  float s = 0.f, sb = 0.f;
  int k0 = seg * 48;
  for (int i = 0; i < 48; ++i){
    int k = k0 + i;
    float w1 = gw1[k * DR_ + n];
    float v = glnw[k] * w1;
    unsigned short vr = f2us(v);
    s  += us2f(vr);
    sb += glnb[k] * w1;
    W1pT[(size_t)n * DP_ + k] = vr;
  }
  pss[seg][nl] = s; psb[seg][nl] = sb;
  __syncthreads();
  if (tid < 64){
    float ts = 0.f, tb = 0.f;
    for (int j = 0; j < 8; ++j){ ts += pss[j][tid]; tb += psb[j][tid]; }
    s1[blockIdx.x * 64 + tid] = ts;
    b1p[blockIdx.x * 64 + tid] = gb1[blockIdx.x * 64 + tid] + tb;
  }
}

// ---------------- S0: xb = bf16(pt + lp) + LN stats. 8 rows/block ----------
__global__ __launch_bounds__(512) void k_xform(
    const float* __restrict__ pt, const float* __restrict__ lp,
    ushort_t* __restrict__ xb, float* __restrict__ mu, float* __restrict__ rsg){
  int tid = threadIdx.x, w = tid >> 6, lane = tid & 63;
  size_t r = (size_t)blockIdx.x * 8 + w;
  int p = (int)(r & (P_ - 1));
  const float* xr = pt + r * DP_ + lane * 6;
  const float* lr = lp + (size_t)p * DP_ + lane * 6;
  float x[6];
  float s = 0.f, ss = 0.f;
#pragma unroll
  for (int i = 0; i < 6; i += 2){
    float2 a = *(const float2*)(xr + i);
    float2 b = *(const float2*)(lr + i);
    x[i] = a.x + b.x; x[i + 1] = a.y + b.y;
  }
#pragma unroll
  for (int i = 0; i < 6; ++i){ s += x[i]; ss += x[i] * x[i]; }
  s = wred_sum(s); ss = wred_sum(ss);
  if (lane == 0){
    float m = s * (1.f / DP_);
    float var = ss * (1.f / DP_) - m * m;
    mu[r] = m;
    rsg[r] = rsqrtf(var + 1e-5f);
  }
  ushort_t* xw = xb + r * DP_ + lane * 6;
#pragma unroll
  for (int i = 0; i < 6; i += 2){
    ushort2 u2; u2.x = f2us(x[i]); u2.y = f2us(x[i + 1]);
    *(ushort2*)(xw + i) = u2;
  }
}

// ---- P2 fused: gate GEMM (xb bf16 via global_load_lds; B direct from L2)
//      + folded LN + gelu + logit + softmax + attention pooling.
__global__ __launch_bounds__(512, 4) void k_gate_pool(
    const ushort_t* __restrict__ xb,   // (65536 x 384) bf16
    const ushort_t* __restrict__ BT,   // W1pT (512 x 384) bf16
    const float* __restrict__ mu, const float* __restrict__ rsg,
    const float* __restrict__ s1, const float* __restrict__ b1p,
    const float* __restrict__ w2, const int* __restrict__ pmask,
    float* __restrict__ pooled){
  __shared__ __align__(16) ushort_t Abuf[64 * 64];   // 8 KB, swizzled chunks
  __shared__ float logit_lds[64];
  __shared__ float smu[64], srs[64];
  __shared__ float attn[64];
  int tid = threadIdx.x;
  int lane = tid & 63, w = tid >> 6;
  int t = lane & 15, g = lane >> 4;
  long r0 = (long)blockIdx.x * 64;
  if (tid < 64){
    logit_lds[tid] = 0.f;
    smu[tid] = mu[r0 + tid];
    srs[tid] = rsg[r0 + tid];
  }

  f32x4 acc[4][4];
#pragma unroll
  for (int m = 0; m < 4; ++m)
#pragma unroll
    for (int n = 0; n < 4; ++n) acc[m][n] = (f32x4){0.f, 0.f, 0.f, 0.f};

  // per-lane staging source (pre-swizzled): wave w stages rows w*8..w*8+7
  int arow8 = (w << 3) + (lane >> 3);
  int akc = lane & 7;
  const ushort_t* asrc0 = xb + (size_t)(r0 + arow8) * DP_ + ((akc ^ (arow8 & 7)) << 3);
  ushort_t* adst = Abuf + (w << 9);   // wave-uniform base; HW adds lane*16B

  for (int kt = 0; kt < 6; ++kt){
    __syncthreads();                  // previous compute done before overwrite
    GLOAD16(asrc0 + kt * 64, adst);
    __syncthreads();                  // drain: stage complete
#pragma unroll
    for (int kk = 0; kk < 2; ++kk){
      int ch = kk * 4 + g;
      bf16x8 af[4], bfr[4];
#pragma unroll
      for (int m = 0; m < 4; ++m){
        int row = m * 16 + t;
        af[m] = *(const bf16x8*)(Abuf + row * 64 + ((ch ^ (row & 7)) << 3));
      }
#pragma unroll
      for (int n = 0; n < 4; ++n){
        int rowb = w * 64 + n * 16 + t;
        bfr[n] = *(const bf16x8*)(BT + (size_t)rowb * DP_ + kt * 64 + ch * 8);
      }
#pragma unroll
      for (int m = 0; m < 4; ++m)
#pragma unroll
        for (int n = 0; n < 4; ++n)
          acc[m][n] = __builtin_amdgcn_mfma_f32_16x16x32_bf16(af[m], bfr[n], acc[m][n], 0, 0, 0);
    }
  }
  __syncthreads();

  // epilogue: folded LN + gelu + reduce against gate_w2
  float w2c[4], s1c[4], b1c[4];
#pragma unroll
  for (int n = 0; n < 4; ++n){
    int c = w * 64 + n * 16 + t;
    w2c[n] = w2[c]; s1c[n] = s1[c]; b1c[n] = b1p[c];
  }
#pragma unroll
  for (int m = 0; m < 4; ++m){
#pragma unroll
    for (int j = 0; j < 4; ++j){
      int rl = m * 16 + g * 4 + j;
      float mur = smu[rl], rs = srs[rl];
      float part = 0.f;
#pragma unroll
      for (int n = 0; n < 4; ++n){
        float gp = rs * acc[m][n][j] - mur * rs * s1c[n] + b1c[n];
        part += gelu_f(gp) * w2c[n];
      }
#pragma unroll
      for (int msk = 1; msk < 16; msk <<= 1) part += __shfl_xor(part, msk, 64);
      if (t == 0) atomicAdd(&logit_lds[rl], part);
    }
  }
  __syncthreads();

  // masked softmax over the 64 patches (gate_b2 cancels in softmax)
  if (tid < 64){
    int mk = pmask[r0 + tid];
    float lv = logit_lds[tid];
    float lm = mk ? lv : -3.4e38f;
    float M = lm;
#pragma unroll
    for (int m2 = 1; m2 < 64; m2 <<= 1) M = fmaxf(M, __shfl_xor(M, m2, 64));
    float e = mk ? __expf(lv - M) : 0.f;
    float S = e;
#pragma unroll
    for (int m2 = 1; m2 < 64; m2 <<= 1) S += __shfl_xor(S, m2, 64);
    float a = (S > 0.f) ? e / S : 0.f;
    float S2 = a;
#pragma unroll
    for (int m2 = 1; m2 < 64; m2 <<= 1) S2 += __shfl_xor(S2, m2, 64);
    attn[tid] = a / fmaxf(S2, 1e-6f);
  }
  __syncthreads();

  // attention pooling from xb (L2/L3-hot)
  if (tid < DP_){
    float accp = 0.f;
#pragma unroll 4
    for (int p = 0; p < P_; ++p)
      accp += attn[p] * us2f(xb[(size_t)(r0 + p) * DP_ + tid]);
    pooled[(long)blockIdx.x * DP_ + tid] = accp;
  }
}

// ---------------- R1+R3+R4 fused: region MLP -> in_proj -> x_proj ----------
// 2 rows/block (512 blocks); all GEMV k-loops unrolled x8 with weight-register
// preload so 8-16 L2 loads are in flight per wave (latency-bound fix).
__global__ __launch_bounds__(512) void k_region(
    const float* __restrict__ pooled,
    const float* __restrict__ ln1w, const float* __restrict__ ln1b,
    const float* __restrict__ pw1, const float* __restrict__ pb1,
    const float* __restrict__ pw2, const float* __restrict__ pb2,
    const float* __restrict__ ln2w, const float* __restrict__ ln2b,
    const float* __restrict__ inpw, const float* __restrict__ xpw,
    const float* __restrict__ dtw, const float* __restrict__ dtb,
    float* __restrict__ region, float* __restrict__ uT, float* __restrict__ zT,
    float* __restrict__ deltaT, float* __restrict__ BmT, float* __restrict__ CmT){
  __shared__ float xr[2][DP_];
  __shared__ float p1[2][DR_];
  __shared__ float rg[2][DR_];
  __shared__ float us[2][DR_];
  __shared__ float ps[4][2][128];
  __shared__ float prm[2][RK_ + 2 * N_];
  __shared__ float red[24];
  int tid = threadIdx.x;
  int r0 = blockIdx.x * 2;
  for (int i = tid; i < 2 * DP_; i += 512) xr[i / DP_][i % DP_] = pooled[(long)r0 * DP_ + i];
  __syncthreads();
  // ---- LN1
  float v0 = (tid < DP_) ? xr[0][tid] : 0.f;
  float v1 = (tid < DP_) ? xr[1][tid] : 0.f;
  float s0 = v0, s1v = v1;
  block_sum2(s0, s1v, red);
  float dv0 = (tid < DP_) ? (v0 - s0 * (1.f / DP_)) : 0.f;
  float dv1 = (tid < DP_) ? (v1 - s1v * (1.f / DP_)) : 0.f;
  float q0 = dv0 * dv0, q1 = dv1 * dv1;
  block_sum2(q0, q1, red);
  if (tid < DP_){
    float lw = ln1w[tid], lb = ln1b[tid];
    xr[0][tid] = dv0 * rsqrtf(q0 * (1.f / DP_) + 1e-5f) * lw + lb;
    xr[1][tid] = dv1 * rsqrtf(q1 * (1.f / DP_) + 1e-5f) * lw + lb;
  }
  __syncthreads();
  // ---- W1 + gelu (K=384, unroll 8)
  {
    float pb = pb1[tid];
    float a0 = pb, a1 = pb;
    for (int k0 = 0; k0 < DP_; k0 += 8){
      float wv[8];
#pragma unroll
      for (int j = 0; j < 8; ++j) wv[j] = pw1[(k0 + j) * DR_ + tid];
#pragma unroll
      for (int j = 0; j < 8; ++j){
        a0 = fmaf(xr[0][k0 + j], wv[j], a0);
        a1 = fmaf(xr[1][k0 + j], wv[j], a1);
      }
    }
    p1[0][tid] = gelu_f(a0); p1[1][tid] = gelu_f(a1);
  }
  __syncthreads();
  // ---- W2 (K=512, unroll 8)
  float qq0, qq1;
  {
    float pb = pb2[tid];
    float a0 = pb, a1 = pb;
    for (int k0 = 0; k0 < DR_; k0 += 8){
      float wv[8];
#pragma unroll
      for (int j = 0; j < 8; ++j) wv[j] = pw2[(k0 + j) * DR_ + tid];
#pragma unroll
      for (int j = 0; j < 8; ++j){
        a0 = fmaf(p1[0][k0 + j], wv[j], a0);
        a1 = fmaf(p1[1][k0 + j], wv[j], a1);
      }
    }
    qq0 = a0; qq1 = a1;
  }
  // ---- LN2 + nan fix + l2norm
  {
    float m0 = qq0, m1 = qq1;
    block_sum2(m0, m1, red);
    float d0 = qq0 - m0 * (1.f / DR_), d1 = qq1 - m1 * (1.f / DR_);
    float w0 = d0 * d0, w1 = d1 * d1;
    block_sum2(w0, w1, red);
    float lw = ln2w[tid], lb = ln2b[tid];
    float o0 = d0 * rsqrtf(w0 * (1.f / DR_) + 1e-5f) * lw + lb;
    float o1 = d1 * rsqrtf(w1 * (1.f / DR_) + 1e-5f) * lw + lb;
    if (isnan(o0)) o0 = 0.f; else if (isinf(o0)) o0 = (o0 > 0.f) ? 1.f : -1.f;
    if (isnan(o1)) o1 = 0.f; else if (isinf(o1)) o1 = (o1 > 0.f) ? 1.f : -1.f;
    float n0 = o0 * o0, n1 = o1 * o1;
    block_sum2(n0, n1, red);
    float r0v = o0 / fmaxf(sqrtf(n0), 1e-6f);
    float r1v = o1 / fmaxf(sqrtf(n1), 1e-6f);
    rg[0][tid] = r0v; rg[1][tid] = r1v;
    region[(long)r0 * DR_ + tid] = r0v;
    region[(long)(r0 + 1) * DR_ + tid] = r1v;
  }
  __syncthreads();
  // ---- in_proj (K=512, unroll 8; 2 output cols/thread)
  {
    float ua0 = 0.f, ua1 = 0.f, zb0 = 0.f, zb1 = 0.f;
    for (int k0 = 0; k0 < DR_; k0 += 8){
      float w1v[8], w2v[8];
#pragma unroll
      for (int j = 0; j < 8; ++j){
        w1v[j] = inpw[(k0 + j) * 1024 + tid];
        w2v[j] = inpw[(k0 + j) * 1024 + tid + 512];
      }
#pragma unroll
      for (int j = 0; j < 8; ++j){
        float x0 = rg[0][k0 + j], x1 = rg[1][k0 + j];
        ua0 = fmaf(x0, w1v[j], ua0); ua1 = fmaf(x1, w1v[j], ua1);
        zb0 = fmaf(x0, w2v[j], zb0); zb1 = fmaf(x1, w2v[j], zb1);
      }
    }
    us[0][tid] = ua0; us[1][tid] = ua1;
    uT[(long)tid * REGS + r0] = ua0;
    uT[(long)tid * REGS + r0 + 1] = ua1;
    zT[(long)tid * REGS + r0] = zb0;
    zT[(long)tid * REGS + r0 + 1] = zb1;
  }
  __syncthreads();
  // ---- x_proj: K-split 4 segs x 128 cols (unroll 8)
  {
    int sseg = tid >> 7, c = tid & 127;
    float pr0 = 0.f, pr1 = 0.f;
    if (c < RK_ + 2 * N_){
      int kb = sseg * 128;
      for (int k0 = kb; k0 < kb + 128; k0 += 8){
        float wv[8];
#pragma unroll
        for (int j = 0; j < 8; ++j) wv[j] = xpw[(k0 + j) * (RK_ + 2 * N_) + c];
#pragma unroll
        for (int j = 0; j < 8; ++j){
          pr0 = fmaf(us[0][k0 + j], wv[j], pr0);
          pr1 = fmaf(us[1][k0 + j], wv[j], pr1);
        }
      }
    }
    ps[sseg][0][c] = pr0; ps[sseg][1][c] = pr1;
  }
  __syncthreads();
  if (tid < 256){
    int rr2 = tid >> 7, cc = tid & 127;
    if (cc < RK_ + 2 * N_)
      prm[rr2][cc] = ps[0][rr2][cc] + ps[1][rr2][cc] + ps[2][rr2][cc] + ps[3][rr2][cc];
  }
  __syncthreads();
  // ---- dt head -> delta (transposed)
#pragma unroll
  for (int r = 0; r < 2; ++r){
    float aa = dtb[tid];
#pragma unroll
    for (int j = 0; j < RK_; ++j) aa = fmaf(prm[r][j], dtw[j * DR_ + tid], aa);
    float sp = (aa > 20.f) ? aa : log1pf(expf(aa));
    deltaT[(long)tid * REGS + r0 + r] = fminf(sp, 10.f);
  }
  if (tid < N_){
#pragma unroll
    for (int r = 0; r < 2; ++r){
      BmT[(long)tid * REGS + r0 + r] = prm[r][RK_ + tid];
      CmT[(long)tid * REGS + r0 + r] = prm[r][RK_ + N_ + tid];
    }
  }
}

// ---------------- R5: parallel-prefix selective scan (coalesced inputs) ----
__global__ __launch_bounds__(256) void k_scan(
    const float* __restrict__ deltaT, const float* __restrict__ uT,
    const float* __restrict__ zT, const float* __restrict__ BmT,
    const float* __restrict__ CmT, const float* __restrict__ alog,
    const float* __restrict__ Dp, float* __restrict__ ys){
  __shared__ float sAn[N_];
  __shared__ float sA[N_][4];
  __shared__ float sB[N_][4];
  int tid = threadIdx.x, lane = tid & 63, w = tid >> 6;
  int ch = blockIdx.x;
  int b = ch >> 9, d = ch & (DR_ - 1);
  if (tid < N_) sAn[tid] = -fminf(__expf(alog[d * N_ + tid]), 10000.f);
  long col = (long)b * R_ + tid;
  float dl = deltaT[(long)d * REGS + col];
  float uu = uT[(long)d * REGS + col];
  float zz = zT[(long)d * REGS + col];
  float Dd = Dp[d];
  float part = 0.f;
  __syncthreads();
  for (int nc = 0; nc < 6; ++nc){
    float bmv[8], cmv[8];
#pragma unroll
    for (int j = 0; j < 8; ++j){
      bmv[j] = BmT[(long)(nc * 8 + j) * REGS + col];
      cmv[j] = CmT[(long)(nc * 8 + j) * REGS + col];
    }
    float aA[8], aB[8];
#pragma unroll
    for (int j = 0; j < 8; ++j){
      int n = nc * 8 + j;
      float cc = fminf(fmaxf(dl * sAn[n], -30.f), 30.f);
      float a = exp2f(cc * 1.44269504f);
      float bv = dl * bmv[j] * uu;
#pragma unroll
      for (int s = 1; s < 64; s <<= 1){
        float a_sh = __shfl_up(a, (unsigned)s, 64);
        float b_sh = __shfl_up(bv, (unsigned)s, 64);
        float nb = fmaf(a, b_sh, bv);
        float na = a * a_sh;
        if (lane >= s){ bv = nb; a = na; }
      }
      aA[j] = a; aB[j] = bv;
      if (lane == 63){ sA[n][w] = a; sB[n][w] = bv; }
    }
    __syncthreads();
#pragma unroll
    for (int j = 0; j < 8; ++j){
      int n = nc * 8 + j;
      float hin = 0.f;
#pragma unroll
      for (int tt = 0; tt < 3; ++tt){
        if (tt < w) hin = sA[n][tt] * hin + sB[n][tt];
      }
      float h = fmaf(aA[j], hin, aB[j]);
      part = fmaf(cmv[j], h, part);
    }
    if (nc < 5) __syncthreads();
  }
  float yv = part + Dd * uu;
  float sz = zz / (1.f + __expf(-zz));
  ys[col * DR_ + d] = yv * sz;
}

// ---------------- R6: out_proj + residual + final LN + l2norm, 4 rows ------
__global__ __launch_bounds__(512) void k_out(
    const float* __restrict__ ys, const float* __restrict__ W,
    const float* __restrict__ region, const float* __restrict__ lnw,
    const float* __restrict__ lnb, float* __restrict__ outp,
    float* __restrict__ rt){
  __shared__ float yr[4][DR_];
  __shared__ float red[40];
  int tid = threadIdx.x;
  int r0 = blockIdx.x * 4;
  for (int i = tid; i < 4 * DR_; i += 512) yr[i >> 9][i & 511] = ys[(long)r0 * DR_ + i];
  __syncthreads();
  float y[4] = {0,0,0,0};
  for (int k0 = 0; k0 < DR_; k0 += 8){
    float wv[8];
#pragma unroll
    for (int j = 0; j < 8; ++j) wv[j] = W[(k0 + j) * DR_ + tid];
#pragma unroll
    for (int j = 0; j < 8; ++j){
#pragma unroll
      for (int i = 0; i < 4; ++i) y[i] = fmaf(yr[i][k0 + j], wv[j], y[i]);
    }
  }
  float v[4], t4[4];
#pragma unroll
  for (int i = 0; i < 4; ++i){
    if (isnan(y[i])) y[i] = 0.f; else if (isinf(y[i])) y[i] = (y[i] > 0.f) ? 1.f : -1.f;
    v[i] = region[(long)(r0 + i) * DR_ + tid] + y[i];
    t4[i] = v[i];
  }
  block_sum4(t4, red);
  float dv[4];
#pragma unroll
  for (int i = 0; i < 4; ++i){ dv[i] = v[i] - t4[i] * (1.f / DR_); t4[i] = dv[i] * dv[i]; }
  block_sum4(t4, red);
  float o[4];
  float lw = lnw[tid], lb = lnb[tid];
#pragma unroll
  for (int i = 0; i < 4; ++i){
    o[i] = dv[i] * rsqrtf(t4[i] * (1.f / DR_) + 1e-5f) * lw + lb;
    outp[(long)(r0 + i) * DR_ + tid] = o[i];
    t4[i] = o[i] * o[i];
  }
  block_sum4(t4, red);
#pragma unroll
  for (int i = 0; i < 4; ++i)
    rt[(long)(r0 + i) * DR_ + tid] = o[i] / fmaxf(sqrtf(t4[i]), 1e-6f);
}

// ---------------- R7: similarity losses, 4 query rows per block ------------
__global__ __launch_bounds__(512) void k_loss(
    const float* __restrict__ rt, const int* __restrict__ nearm,
    const int* __restrict__ farm, float* __restrict__ accum){
  __shared__ __align__(16) float ar[4][DR_];
  __shared__ float ps[2][4][256];
  __shared__ float wsum[8][4];
  int blk = blockIdx.x, tid = threadIdx.x;
  int b = blk >> 6, q0 = (blk & 63) * 4;
  const float* rtb = rt + (long)b * R_ * DR_;
  for (int i = tid; i < 4 * DR_; i += 512) ar[i >> 9][i & 511] = rtb[(long)q0 * DR_ + i];
  __syncthreads();
  int s = tid & 255, h = tid >> 8;
  const float* rsrow = rtb + (long)s * DR_ + h * 256;
  float dq[4] = {0.f, 0.f, 0.f, 0.f};
  for (int k = 0; k < 256; k += 4){
    float4 yv = *(const float4*)(rsrow + k);
#pragma unroll
    for (int q = 0; q < 4; ++q){
      float4 x = *(const float4*)(&ar[q][h * 256 + k]);
      dq[q] += x.x * yv.x + x.y * yv.y + x.z * yv.z + x.w * yv.w;
    }
  }
#pragma unroll
  for (int q = 0; q < 4; ++q) ps[h][q][s] = dq[q];
  __syncthreads();
  float nl = 0.f, fl = 0.f, nc = 0.f, fc = 0.f;
  if (tid < 256){
#pragma unroll
    for (int q = 0; q < 4; ++q){
      float dot = ps[0][q][tid] + ps[1][q][tid];
      int nm = nearm[(q0 + q) * R_ + tid], fm = farm[(q0 + q) * R_ + tid];
      if (nm){ nl += 1.f - dot; if (b == 0) nc += 1.f; }
      if (fm){ fl += fmaxf(dot - 0.2f, 0.f); if (b == 0) fc += 1.f; }
    }
  }
  nl = wred_sum(nl); fl = wred_sum(fl); nc = wred_sum(nc); fc = wred_sum(fc);
  int w = tid >> 6, lane = tid & 63;
  if (lane == 0){ wsum[w][0] = nl; wsum[w][1] = fl; wsum[w][2] = nc; wsum[w][3] = fc; }
  __syncthreads();
  if (tid == 0){
    float a0 = 0, a1 = 0, a2 = 0, a3 = 0;
    for (int i = 0; i < 8; i++){ a0 += wsum[i][0]; a1 += wsum[i][1]; a2 += wsum[i][2]; a3 += wsum[i][3]; }
    atomicAdd(&accum[0], a0); atomicAdd(&accum[1], a1);
    if (b == 0){ atomicAdd(&accum[2], a2); atomicAdd(&accum[3], a3); }
  }
}

__global__ void k_final(const float* __restrict__ accum, float* __restrict__ outp){
  if (threadIdx.x == 0){
    float loss = accum[0] / fmaxf(accum[2], 1.f) + accum[1] / fmaxf(accum[3], 1.f);
    outp[REGS * DR_] = loss;
  }
}

extern "C" void kernel_launch(void* const* d_in, const int* in_sizes, int n_in,
                              void* d_out, int out_size, void* d_ws, size_t ws_size,
                              hipStream_t stream){
  const float* pt    = (const float*)d_in[0];
  const int*   pmask = (const int*)d_in[1];
  const int*   nearm = (const int*)d_in[2];
  const int*   farm  = (const int*)d_in[3];
  const float* lp    = (const float*)d_in[4];
  const float* glnw  = (const float*)d_in[5];
  const float* glnb  = (const float*)d_in[6];
  const float* gw1   = (const float*)d_in[7];
  const float* gb1   = (const float*)d_in[8];
  const float* gw2   = (const float*)d_in[9];
  const float* pln1w = (const float*)d_in[11];
  const float* pln1b = (const float*)d_in[12];
  const float* pw1   = (const float*)d_in[13];
  const float* pb1   = (const float*)d_in[14];
  const float* pw2   = (const float*)d_in[15];
  const float* pb2   = (const float*)d_in[16];
  const float* pln2w = (const float*)d_in[17];
  const float* pln2b = (const float*)d_in[18];
  const float* inpw  = (const float*)d_in[19];
  const float* xpw   = (const float*)d_in[20];
  const float* dtw   = (const float*)d_in[21];
  const float* dtb   = (const float*)d_in[22];
  const float* alog  = (const float*)d_in[23];
  const float* dpar  = (const float*)d_in[24];
  const float* opw   = (const float*)d_in[25];
  const float* slnw  = (const float*)d_in[26];
  const float* slnb  = (const float*)d_in[27];

  char* ws = (char*)d_ws;
  size_t off = 0;
  auto alloc = [&](size_t bytes){ size_t o = off; off += (bytes + 255) & ~(size_t)255; return o; };
  ushort_t* W1pT = (ushort_t*)(ws + alloc((size_t)DR_ * DP_ * 2));
  float* s1     = (float*)(ws + alloc(DR_ * 4));
  float* b1p    = (float*)(ws + alloc(DR_ * 4));
  ushort_t* xb  = (ushort_t*)(ws + alloc((size_t)MROWS * DP_ * 2));
  float* mu     = (float*)(ws + alloc((size_t)MROWS * 4));
  float* rsg    = (float*)(ws + alloc((size_t)MROWS * 4));
  float* pooled = (float*)(ws + alloc((size_t)REGS * DP_ * 4));
  float* region = (float*)(ws + alloc((size_t)REGS * DR_ * 4));
  float* uT     = (float*)(ws + alloc((size_t)REGS * DR_ * 4));
  float* zT     = (float*)(ws + alloc((size_t)REGS * DR_ * 4));
  float* deltaT = (float*)(ws + alloc((size_t)REGS * DR_ * 4));
  float* BmT    = (float*)(ws + alloc((size_t)REGS * N_ * 4));
  float* CmT    = (float*)(ws + alloc((size_t)REGS * N_ * 4));
  float* ys     = (float*)(ws + alloc((size_t)REGS * DR_ * 4));
  float* rt     = (float*)(ws + alloc((size_t)REGS * DR_ * 4));
  float* accum  = (float*)(ws + alloc(4 * 4));

  float* outp = (float*)d_out;

  k_prep<<<dim3(8), dim3(512), 0, stream>>>(gw1, glnw, glnb, gb1, W1pT, s1, b1p, accum);
  k_xform<<<dim3(MROWS / 8), dim3(512), 0, stream>>>(pt, lp, xb, mu, rsg);
  k_gate_pool<<<dim3(REGS), dim3(512), 0, stream>>>(xb, W1pT, mu, rsg, s1, b1p, gw2, pmask, pooled);
  k_region<<<dim3(REGS / 2), dim3(512), 0, stream>>>(pooled, pln1w, pln1b, pw1, pb1, pw2, pb2, pln2w, pln2b,
                                                     inpw, xpw, dtw, dtb, region, uT, zT, deltaT, BmT, CmT);
  k_scan<<<dim3(B_ * DR_), dim3(256), 0, stream>>>(deltaT, uT, zT, BmT, CmT, alog, dpar, ys);
  k_out<<<dim3(REGS / 4), dim3(512), 0, stream>>>(ys, opw, region, slnw, slnb, outp, rt);
  k_loss<<<dim3(REGS / 4), dim3(512), 0, stream>>>(rt, nearm, farm, accum);
  k_final<<<dim3(1), dim3(64), 0, stream>>>(accum, outp);
}

// Round 7
// 322.108 us; speedup vs baseline: 2.0022x; 1.0258x over previous
//
#include <hip/hip_runtime.h>
#include <hip/hip_bf16.h>
#include <math.h>

#define B_ 4
#define R_ 256
#define P_ 64
#define DP_ 384
#define DR_ 512
#define N_ 48
#define RK_ 24
#define MROWS (B_*R_*P_)   /* 65536 */
#define REGS  (B_*R_)      /* 1024  */

typedef unsigned short ushort_t;
typedef __attribute__((ext_vector_type(8))) short bf16x8;
typedef __attribute__((ext_vector_type(4))) float f32x4;

#define GLOAD16(g, l) __builtin_amdgcn_global_load_lds( \
    (const __attribute__((address_space(1))) unsigned int*)(g), \
    (__attribute__((address_space(3))) unsigned int*)(l), 16, 0, 0)

// bf16 weight blob segment offsets (elements)
#define OFF_PW1  0
#define OFF_PW2  196608
#define OFF_INPW 458752
#define OFF_XPW  983040
#define OFF_DTW  1044480
#define NW_TOT   1056768

__device__ __forceinline__ float us2f(unsigned short u){
  union { unsigned int i; float f; } x; x.i = ((unsigned int)u) << 16; return x.f;
}
__device__ __forceinline__ unsigned short f2us(float f){
  __hip_bfloat16 h = __float2bfloat16(f);
  return *reinterpret_cast<unsigned short*>(&h);
}
__device__ __forceinline__ float gelu_f(float x){
  return 0.5f * x * (1.0f + erff(x * 0.70710678118654752f));
}
__device__ __forceinline__ float wred_sum(float v){
#pragma unroll
  for (int m = 1; m < 64; m <<= 1) v += __shfl_xor(v, m, 64);
  return v;
}
// 4 simultaneous block-wide sums (512-thread blocks); s >= 40 floats
__device__ __forceinline__ void block_sum4(float v[4], float* s){
  int lane = threadIdx.x & 63, wid = threadIdx.x >> 6;
#pragma unroll
  for (int i = 0; i < 4; ++i){
    float x = v[i];
#pragma unroll
    for (int m = 1; m < 64; m <<= 1) x += __shfl_xor(x, m, 64);
    if (lane == 0) s[wid * 4 + i] = x;
  }
  __syncthreads();
  if (threadIdx.x < 4){
    float t = 0.f;
    for (int t2 = 0; t2 < 8; ++t2) t += s[t2 * 4 + threadIdx.x];
    s[32 + threadIdx.x] = t;
  }
  __syncthreads();
#pragma unroll
  for (int i = 0; i < 4; ++i) v[i] = s[32 + i];
  __syncthreads();
}
// 2 simultaneous block-wide sums (512-thread blocks); s >= 18 floats
__device__ __forceinline__ void block_sum2(float& a, float& b, float* s){
  int lane = threadIdx.x & 63, wid = threadIdx.x >> 6;
  float x = a, y = b;
#pragma unroll
  for (int m = 1; m < 64; m <<= 1){ x += __shfl_xor(x, m, 64); y += __shfl_xor(y, m, 64); }
  if (lane == 0){ s[wid * 2] = x; s[wid * 2 + 1] = y; }
  __syncthreads();
  if (threadIdx.x < 2){
    float t = 0.f;
    for (int j = 0; j < 8; ++j) t += s[j * 2 + threadIdx.x];
    s[16 + threadIdx.x] = t;
  }
  __syncthreads();
  a = s[16]; b = s[17];
  __syncthreads();
}

// ---------------- C0: weight prep, parallel. 8 blocks x 512 ----------------
__global__ __launch_bounds__(512) void k_prep(
    const float* __restrict__ gw1, const float* __restrict__ glnw,
    const float* __restrict__ glnb, const float* __restrict__ gb1,
    ushort_t* __restrict__ W1pT, float* __restrict__ s1,
    float* __restrict__ b1p, float* __restrict__ accum){
  __shared__ float pss[8][64], psb[8][64];
  int tid = threadIdx.x, seg = tid >> 6, nl = tid & 63;
  int n = blockIdx.x * 64 + nl;
  if (blockIdx.x == 0 && tid < 4) accum[tid] = 0.f;
  float s = 0.f, sb = 0.f;
  int k0 = seg * 48;
  for (int i = 0; i < 48; ++i){
    int k = k0 + i;
    float w1 = gw1[k * DR_ + n];
    float v = glnw[k] * w1;
    unsigned short vr = f2us(v);
    s  += us2f(vr);
    sb += glnb[k] * w1;
    W1pT[(size_t)n * DP_ + k] = vr;
  }
  pss[seg][nl] = s; psb[seg][nl] = sb;
  __syncthreads();
  if (tid < 64){
    float ts = 0.f, tb = 0.f;
    for (int j = 0; j < 8; ++j){ ts += pss[j][tid]; tb += psb[j][tid]; }
    s1[blockIdx.x * 64 + tid] = ts;
    b1p[blockIdx.x * 64 + tid] = gb1[blockIdx.x * 64 + tid] + tb;
  }
}

// ---------------- C1: cast region-chain weights f32 -> bf16 blob -----------
__global__ __launch_bounds__(512) void k_cast(
    const float* __restrict__ pw1, const float* __restrict__ pw2,
    const float* __restrict__ inpw, const float* __restrict__ xpw,
    const float* __restrict__ dtw, ushort_t* __restrict__ dst){
  int i = (blockIdx.x * 512 + threadIdx.x) * 4;
  if (i >= NW_TOT) return;
  const float* s; int off;
  if (i < OFF_PW2){ s = pw1; off = OFF_PW1; }
  else if (i < OFF_INPW){ s = pw2; off = OFF_PW2; }
  else if (i < OFF_XPW){ s = inpw; off = OFF_INPW; }
  else if (i < OFF_DTW){ s = xpw; off = OFF_XPW; }
  else { s = dtw; off = OFF_DTW; }
  float4 v = *(const float4*)(s + (i - off));
  ushort_t* d = dst + i;
  d[0] = f2us(v.x); d[1] = f2us(v.y); d[2] = f2us(v.z); d[3] = f2us(v.w);
}

// ---------------- S0: xb = bf16(pt + lp) + LN stats. 8 rows/block ----------
__global__ __launch_bounds__(512) void k_xform(
    const float* __restrict__ pt, const float* __restrict__ lp,
    ushort_t* __restrict__ xb, float* __restrict__ mu, float* __restrict__ rsg){
  int tid = threadIdx.x, w = tid >> 6, lane = tid & 63;
  size_t r = (size_t)blockIdx.x * 8 + w;
  int p = (int)(r & (P_ - 1));
  const float* xr = pt + r * DP_ + lane * 6;
  const float* lr = lp + (size_t)p * DP_ + lane * 6;
  float x[6];
  float s = 0.f, ss = 0.f;
#pragma unroll
  for (int i = 0; i < 6; i += 2){
    float2 a = *(const float2*)(xr + i);
    float2 b = *(const float2*)(lr + i);
    x[i] = a.x + b.x; x[i + 1] = a.y + b.y;
  }
#pragma unroll
  for (int i = 0; i < 6; ++i){ s += x[i]; ss += x[i] * x[i]; }
  s = wred_sum(s); ss = wred_sum(ss);
  if (lane == 0){
    float m = s * (1.f / DP_);
    float var = ss * (1.f / DP_) - m * m;
    mu[r] = m;
    rsg[r] = rsqrtf(var + 1e-5f);
  }
  ushort_t* xw = xb + r * DP_ + lane * 6;
#pragma unroll
  for (int i = 0; i < 6; i += 2){
    ushort2 u2; u2.x = f2us(x[i]); u2.y = f2us(x[i + 1]);
    *(ushort2*)(xw + i) = u2;
  }
}

// ---- P2 fused: gate GEMM (double-buffered global_load_lds A; B from L2)
//      + folded LN + gelu + logit + softmax + attention pooling.
__global__ __launch_bounds__(512, 4) void k_gate_pool(
    const ushort_t* __restrict__ xb,   // (65536 x 384) bf16
    const ushort_t* __restrict__ BT,   // W1pT (512 x 384) bf16
    const float* __restrict__ mu, const float* __restrict__ rsg,
    const float* __restrict__ s1, const float* __restrict__ b1p,
    const float* __restrict__ w2, const int* __restrict__ pmask,
    float* __restrict__ pooled){
  __shared__ __align__(16) ushort_t Abuf[2][64 * 64];   // 2 x 8 KB, swizzled
  __shared__ float logit_lds[64];
  __shared__ float smu[64], srs[64];
  __shared__ float attn[64];
  int tid = threadIdx.x;
  int lane = tid & 63, w = tid >> 6;
  int t = lane & 15, g = lane >> 4;
  long r0 = (long)blockIdx.x * 64;
  if (tid < 64){
    logit_lds[tid] = 0.f;
    smu[tid] = mu[r0 + tid];
    srs[tid] = rsg[r0 + tid];
  }

  f32x4 acc[4][4];
#pragma unroll
  for (int m = 0; m < 4; ++m)
#pragma unroll
    for (int n = 0; n < 4; ++n) acc[m][n] = (f32x4){0.f, 0.f, 0.f, 0.f};

  // per-lane staging source (pre-swizzled): wave w stages rows w*8..w*8+7
  int arow8 = (w << 3) + (lane >> 3);
  int akc = lane & 7;
  const ushort_t* asrc0 = xb + (size_t)(r0 + arow8) * DP_ + ((akc ^ (arow8 & 7)) << 3);
  ushort_t* adst0 = Abuf[0] + (w << 9);
  ushort_t* adst1 = Abuf[1] + (w << 9);

  GLOAD16(asrc0, adst0);
  __syncthreads();                    // drain prologue stage

  for (int kt = 0; kt < 6; ++kt){
    if (kt < 5) GLOAD16(asrc0 + (kt + 1) * 64, (kt & 1) ? adst0 : adst1);
    const ushort_t* cbuf = (kt & 1) ? Abuf[1] : Abuf[0];
    // load all 8 B fragments for this K-step up front (L2-resident)
    bf16x8 bfr[2][4];
#pragma unroll
    for (int kk = 0; kk < 2; ++kk)
#pragma unroll
      for (int n = 0; n < 4; ++n){
        int rowb = w * 64 + n * 16 + t;
        bfr[kk][n] = *(const bf16x8*)(BT + (size_t)rowb * DP_ + kt * 64 + (kk * 4 + g) * 8);
      }
#pragma unroll
    for (int kk = 0; kk < 2; ++kk){
      int ch = kk * 4 + g;
      bf16x8 af[4];
#pragma unroll
      for (int m = 0; m < 4; ++m){
        int row = m * 16 + t;
        af[m] = *(const bf16x8*)(cbuf + row * 64 + ((ch ^ (row & 7)) << 3));
      }
#pragma unroll
      for (int m = 0; m < 4; ++m)
#pragma unroll
        for (int n = 0; n < 4; ++n)
          acc[m][n] = __builtin_amdgcn_mfma_f32_16x16x32_bf16(af[m], bfr[kk][n], acc[m][n], 0, 0, 0);
    }
    __syncthreads();                  // stage kt+1 complete; buffer reuse safe
  }

  // epilogue: folded LN + gelu + reduce against gate_w2
  float w2c[4], s1c[4], b1c[4];
#pragma unroll
  for (int n = 0; n < 4; ++n){
    int c = w * 64 + n * 16 + t;
    w2c[n] = w2[c]; s1c[n] = s1[c]; b1c[n] = b1p[c];
  }
#pragma unroll
  for (int m = 0; m < 4; ++m){
#pragma unroll
    for (int j = 0; j < 4; ++j){
      int rl = m * 16 + g * 4 + j;
      float mur = smu[rl], rs = srs[rl];
      float part = 0.f;
#pragma unroll
      for (int n = 0; n < 4; ++n){
        float gp = rs * acc[m][n][j] - mur * rs * s1c[n] + b1c[n];
        part += gelu_f(gp) * w2c[n];
      }
#pragma unroll
      for (int msk = 1; msk < 16; msk <<= 1) part += __shfl_xor(part, msk, 64);
      if (t == 0) atomicAdd(&logit_lds[rl], part);
    }
  }
  __syncthreads();

  // masked softmax over the 64 patches (gate_b2 cancels in softmax)
  if (tid < 64){
    int mk = pmask[r0 + tid];
    float lv = logit_lds[tid];
    float lm = mk ? lv : -3.4e38f;
    float M = lm;
#pragma unroll
    for (int m2 = 1; m2 < 64; m2 <<= 1) M = fmaxf(M, __shfl_xor(M, m2, 64));
    float e = mk ? __expf(lv - M) : 0.f;
    float S = e;
#pragma unroll
    for (int m2 = 1; m2 < 64; m2 <<= 1) S += __shfl_xor(S, m2, 64);
    float a = (S > 0.f) ? e / S : 0.f;
    float S2 = a;
#pragma unroll
    for (int m2 = 1; m2 < 64; m2 <<= 1) S2 += __shfl_xor(S2, m2, 64);
    attn[tid] = a / fmaxf(S2, 1e-6f);
  }
  __syncthreads();

  // attention pooling from xb (L2/L3-hot)
  if (tid < DP_){
    float accp = 0.f;
#pragma unroll 4
    for (int p = 0; p < P_; ++p)
      accp += attn[p] * us2f(xb[(size_t)(r0 + p) * DP_ + tid]);
    pooled[(long)blockIdx.x * DP_ + tid] = accp;
  }
}

// ---------------- R1+R3+R4 fused: region MLP -> in_proj -> x_proj ----------
// 2 rows/block; bf16 weights; 16-deep load pipelines.
__global__ __launch_bounds__(512, 4) void k_region(
    const float* __restrict__ pooled,
    const float* __restrict__ ln1w, const float* __restrict__ ln1b,
    const ushort_t* __restrict__ wblob, const float* __restrict__ pb1,
    const float* __restrict__ pb2,
    const float* __restrict__ ln2w, const float* __restrict__ ln2b,
    const float* __restrict__ dtb,
    float* __restrict__ region, float* __restrict__ uT, float* __restrict__ zT,
    float* __restrict__ deltaT, float* __restrict__ BmT, float* __restrict__ CmT){
  const ushort_t* pw1b  = wblob + OFF_PW1;
  const ushort_t* pw2b  = wblob + OFF_PW2;
  const ushort_t* inpwb = wblob + OFF_INPW;
  const ushort_t* xpwb  = wblob + OFF_XPW;
  const ushort_t* dtwb  = wblob + OFF_DTW;
  __shared__ float xr[2][DP_];
  __shared__ float p1[2][DR_];
  __shared__ float rg[2][DR_];
  __shared__ float us[2][DR_];
  __shared__ float ps[4][2][128];
  __shared__ float prm[2][RK_ + 2 * N_];
  __shared__ float red[24];
  int tid = threadIdx.x;
  int r0 = blockIdx.x * 2;
  for (int i = tid; i < 2 * DP_; i += 512) xr[i / DP_][i % DP_] = pooled[(long)r0 * DP_ + i];
  __syncthreads();
  // ---- LN1
  float v0 = (tid < DP_) ? xr[0][tid] : 0.f;
  float v1 = (tid < DP_) ? xr[1][tid] : 0.f;
  float s0 = v0, s1v = v1;
  block_sum2(s0, s1v, red);
  float dv0 = (tid < DP_) ? (v0 - s0 * (1.f / DP_)) : 0.f;
  float dv1 = (tid < DP_) ? (v1 - s1v * (1.f / DP_)) : 0.f;
  float q0 = dv0 * dv0, q1 = dv1 * dv1;
  block_sum2(q0, q1, red);
  if (tid < DP_){
    float lw = ln1w[tid], lb = ln1b[tid];
    xr[0][tid] = dv0 * rsqrtf(q0 * (1.f / DP_) + 1e-5f) * lw + lb;
    xr[1][tid] = dv1 * rsqrtf(q1 * (1.f / DP_) + 1e-5f) * lw + lb;
  }
  __syncthreads();
  // ---- W1 + gelu (K=384, 16-deep)
  {
    float pb = pb1[tid];
    float a0 = pb, a1 = pb;
    for (int k0 = 0; k0 < DP_; k0 += 16){
      ushort_t wv[16];
#pragma unroll
      for (int j = 0; j < 16; ++j) wv[j] = pw1b[(k0 + j) * DR_ + tid];
#pragma unroll
      for (int j = 0; j < 16; ++j){
        float wf = us2f(wv[j]);
        a0 = fmaf(xr[0][k0 + j], wf, a0);
        a1 = fmaf(xr[1][k0 + j], wf, a1);
      }
    }
    p1[0][tid] = gelu_f(a0); p1[1][tid] = gelu_f(a1);
  }
  __syncthreads();
  // ---- W2 (K=512, 16-deep)
  float qq0, qq1;
  {
    float pb = pb2[tid];
    float a0 = pb, a1 = pb;
    for (int k0 = 0; k0 < DR_; k0 += 16){
      ushort_t wv[16];
#pragma unroll
      for (int j = 0; j < 16; ++j) wv[j] = pw2b[(k0 + j) * DR_ + tid];
#pragma unroll
      for (int j = 0; j < 16; ++j){
        float wf = us2f(wv[j]);
        a0 = fmaf(p1[0][k0 + j], wf, a0);
        a1 = fmaf(p1[1][k0 + j], wf, a1);
      }
    }
    qq0 = a0; qq1 = a1;
  }
  // ---- LN2 + nan fix + l2norm
  {
    float m0 = qq0, m1 = qq1;
    block_sum2(m0, m1, red);
    float d0 = qq0 - m0 * (1.f / DR_), d1 = qq1 - m1 * (1.f / DR_);
    float w0 = d0 * d0, w1 = d1 * d1;
    block_sum2(w0, w1, red);
    float lw = ln2w[tid], lb = ln2b[tid];
    float o0 = d0 * rsqrtf(w0 * (1.f / DR_) + 1e-5f) * lw + lb;
    float o1 = d1 * rsqrtf(w1 * (1.f / DR_) + 1e-5f) * lw + lb;
    if (isnan(o0)) o0 = 0.f; else if (isinf(o0)) o0 = (o0 > 0.f) ? 1.f : -1.f;
    if (isnan(o1)) o1 = 0.f; else if (isinf(o1)) o1 = (o1 > 0.f) ? 1.f : -1.f;
    float n0 = o0 * o0, n1 = o1 * o1;
    block_sum2(n0, n1, red);
    float r0v = o0 / fmaxf(sqrtf(n0), 1e-6f);
    float r1v = o1 / fmaxf(sqrtf(n1), 1e-6f);
    rg[0][tid] = r0v; rg[1][tid] = r1v;
    region[(long)r0 * DR_ + tid] = r0v;
    region[(long)(r0 + 1) * DR_ + tid] = r1v;
  }
  __syncthreads();
  // ---- in_proj (K=512, 8-deep x 2 streams = 16 loads in flight)
  {
    float ua0 = 0.f, ua1 = 0.f, zb0 = 0.f, zb1 = 0.f;
    for (int k0 = 0; k0 < DR_; k0 += 8){
      ushort_t w1v[8], w2v[8];
#pragma unroll
      for (int j = 0; j < 8; ++j){
        w1v[j] = inpwb[(k0 + j) * 1024 + tid];
        w2v[j] = inpwb[(k0 + j) * 1024 + tid + 512];
      }
#pragma unroll
      for (int j = 0; j < 8; ++j){
        float x0 = rg[0][k0 + j], x1 = rg[1][k0 + j];
        float wa = us2f(w1v[j]), wb = us2f(w2v[j]);
        ua0 = fmaf(x0, wa, ua0); ua1 = fmaf(x1, wa, ua1);
        zb0 = fmaf(x0, wb, zb0); zb1 = fmaf(x1, wb, zb1);
      }
    }
    us[0][tid] = ua0; us[1][tid] = ua1;
    uT[(long)tid * REGS + r0] = ua0;
    uT[(long)tid * REGS + r0 + 1] = ua1;
    zT[(long)tid * REGS + r0] = zb0;
    zT[(long)tid * REGS + r0 + 1] = zb1;
  }
  __syncthreads();
  // ---- x_proj: K-split 4 segs x 128 cols (16-deep)
  {
    int sseg = tid >> 7, c = tid & 127;
    float pr0 = 0.f, pr1 = 0.f;
    if (c < RK_ + 2 * N_){
      int kb = sseg * 128;
      for (int k0 = kb; k0 < kb + 128; k0 += 16){
        ushort_t wv[16];
#pragma unroll
        for (int j = 0; j < 16; ++j) wv[j] = xpwb[(k0 + j) * (RK_ + 2 * N_) + c];
#pragma unroll
        for (int j = 0; j < 16; ++j){
          float wf = us2f(wv[j]);
          pr0 = fmaf(us[0][k0 + j], wf, pr0);
          pr1 = fmaf(us[1][k0 + j], wf, pr1);
        }
      }
    }
    ps[sseg][0][c] = pr0; ps[sseg][1][c] = pr1;
  }
  __syncthreads();
  if (tid < 256){
    int rr2 = tid >> 7, cc = tid & 127;
    if (cc < RK_ + 2 * N_)
      prm[rr2][cc] = ps[0][rr2][cc] + ps[1][rr2][cc] + ps[2][rr2][cc] + ps[3][rr2][cc];
  }
  __syncthreads();
  // ---- dt head -> delta (transposed)
#pragma unroll
  for (int r = 0; r < 2; ++r){
    float aa = dtb[tid];
#pragma unroll
    for (int j = 0; j < RK_; ++j) aa = fmaf(prm[r][j], us2f(dtwb[j * DR_ + tid]), aa);
    float sp = (aa > 20.f) ? aa : log1pf(expf(aa));
    deltaT[(long)tid * REGS + r0 + r] = fminf(sp, 10.f);
  }
  if (tid < N_){
#pragma unroll
    for (int r = 0; r < 2; ++r){
      BmT[(long)tid * REGS + r0 + r] = prm[r][RK_ + tid];
      CmT[(long)tid * REGS + r0 + r] = prm[r][RK_ + N_ + tid];
    }
  }
}

// ---------------- R5: parallel-prefix selective scan (coalesced inputs) ----
__global__ __launch_bounds__(256) void k_scan(
    const float* __restrict__ deltaT, const float* __restrict__ uT,
    const float* __restrict__ zT, const float* __restrict__ BmT,
    const float* __restrict__ CmT, const float* __restrict__ alog,
    const float* __restrict__ Dp, float* __restrict__ ys){
  __shared__ float sAn[N_];
  __shared__ float sA[N_][4];
  __shared__ float sB[N_][4];
  int tid = threadIdx.x, lane = tid & 63, w = tid >> 6;
  int ch = blockIdx.x;
  int b = ch >> 9, d = ch & (DR_ - 1);
  if (tid < N_) sAn[tid] = -fminf(__expf(alog[d * N_ + tid]), 10000.f);
  long col = (long)b * R_ + tid;
  float dl = deltaT[(long)d * REGS + col];
  float uu = uT[(long)d * REGS + col];
  float zz = zT[(long)d * REGS + col];
  float Dd = Dp[d];
  float part = 0.f;
  __syncthreads();
  for (int nc = 0; nc < 6; ++nc){
    float bmv[8], cmv[8];
#pragma unroll
    for (int j = 0; j < 8; ++j){
      bmv[j] = BmT[(long)(nc * 8 + j) * REGS + col];
      cmv[j] = CmT[(long)(nc * 8 + j) * REGS + col];
    }
    float aA[8], aB[8];
#pragma unroll
    for (int j = 0; j < 8; ++j){
      int n = nc * 8 + j;
      float cc = fminf(fmaxf(dl * sAn[n], -30.f), 30.f);
      float a = exp2f(cc * 1.44269504f);
      float bv = dl * bmv[j] * uu;
#pragma unroll
      for (int s = 1; s < 64; s <<= 1){
        float a_sh = __shfl_up(a, (unsigned)s, 64);
        float b_sh = __shfl_up(bv, (unsigned)s, 64);
        float nb = fmaf(a, b_sh, bv);
        float na = a * a_sh;
        if (lane >= s){ bv = nb; a = na; }
      }
      aA[j] = a; aB[j] = bv;
      if (lane == 63){ sA[n][w] = a; sB[n][w] = bv; }
    }
    __syncthreads();
#pragma unroll
    for (int j = 0; j < 8; ++j){
      int n = nc * 8 + j;
      float hin = 0.f;
#pragma unroll
      for (int tt = 0; tt < 3; ++tt){
        if (tt < w) hin = sA[n][tt] * hin + sB[n][tt];
      }
      float h = fmaf(aA[j], hin, aB[j]);
      part = fmaf(cmv[j], h, part);
    }
    if (nc < 5) __syncthreads();
  }
  float yv = part + Dd * uu;
  float sz = zz / (1.f + __expf(-zz));
  ys[col * DR_ + d] = yv * sz;
}

// ---------------- R6: out_proj + residual + final LN + l2norm, 4 rows ------
__global__ __launch_bounds__(512) void k_out(
    const float* __restrict__ ys, const float* __restrict__ W,
    const float* __restrict__ region, const float* __restrict__ lnw,
    const float* __restrict__ lnb, float* __restrict__ outp,
    float* __restrict__ rt){
  __shared__ float yr[4][DR_];
  __shared__ float red[40];
  int tid = threadIdx.x;
  int r0 = blockIdx.x * 4;
  for (int i = tid; i < 4 * DR_; i += 512) yr[i >> 9][i & 511] = ys[(long)r0 * DR_ + i];
  __syncthreads();
  float y[4] = {0,0,0,0};
  for (int k0 = 0; k0 < DR_; k0 += 8){
    float wv[8];
#pragma unroll
    for (int j = 0; j < 8; ++j) wv[j] = W[(k0 + j) * DR_ + tid];
#pragma unroll
    for (int j = 0; j < 8; ++j){
#pragma unroll
      for (int i = 0; i < 4; ++i) y[i] = fmaf(yr[i][k0 + j], wv[j], y[i]);
    }
  }
  float v[4], t4[4];
#pragma unroll
  for (int i = 0; i < 4; ++i){
    if (isnan(y[i])) y[i] = 0.f; else if (isinf(y[i])) y[i] = (y[i] > 0.f) ? 1.f : -1.f;
    v[i] = region[(long)(r0 + i) * DR_ + tid] + y[i];
    t4[i] = v[i];
  }
  block_sum4(t4, red);
  float dv[4];
#pragma unroll
  for (int i = 0; i < 4; ++i){ dv[i] = v[i] - t4[i] * (1.f / DR_); t4[i] = dv[i] * dv[i]; }
  block_sum4(t4, red);
  float o[4];
  float lw = lnw[tid], lb = lnb[tid];
#pragma unroll
  for (int i = 0; i < 4; ++i){
    o[i] = dv[i] * rsqrtf(t4[i] * (1.f / DR_) + 1e-5f) * lw + lb;
    outp[(long)(r0 + i) * DR_ + tid] = o[i];
    t4[i] = o[i] * o[i];
  }
  block_sum4(t4, red);
#pragma unroll
  for (int i = 0; i < 4; ++i)
    rt[(long)(r0 + i) * DR_ + tid] = o[i] / fmaxf(sqrtf(t4[i]), 1e-6f);
}

// ---------------- R7: similarity losses, 4 query rows per block ------------
__global__ __launch_bounds__(512) void k_loss(
    const float* __restrict__ rt, const int* __restrict__ nearm,
    const int* __restrict__ farm, float* __restrict__ accum){
  __shared__ __align__(16) float ar[4][DR_];
  __shared__ float ps[2][4][256];
  __shared__ float wsum[8][4];
  int blk = blockIdx.x, tid = threadIdx.x;
  int b = blk >> 6, q0 = (blk & 63) * 4;
  const float* rtb = rt + (long)b * R_ * DR_;
  for (int i = tid; i < 4 * DR_; i += 512) ar[i >> 9][i & 511] = rtb[(long)q0 * DR_ + i];
  __syncthreads();
  int s = tid & 255, h = tid >> 8;
  const float* rsrow = rtb + (long)s * DR_ + h * 256;
  float dq[4] = {0.f, 0.f, 0.f, 0.f};
  for (int k = 0; k < 256; k += 4){
    float4 yv = *(const float4*)(rsrow + k);
#pragma unroll
    for (int q = 0; q < 4; ++q){
      float4 x = *(const float4*)(&ar[q][h * 256 + k]);
      dq[q] += x.x * yv.x + x.y * yv.y + x.z * yv.z + x.w * yv.w;
    }
  }
#pragma unroll
  for (int q = 0; q < 4; ++q) ps[h][q][s] = dq[q];
  __syncthreads();
  float nl = 0.f, fl = 0.f, nc = 0.f, fc = 0.f;
  if (tid < 256){
#pragma unroll
    for (int q = 0; q < 4; ++q){
      float dot = ps[0][q][tid] + ps[1][q][tid];
      int nm = nearm[(q0 + q) * R_ + tid], fm = farm[(q0 + q) * R_ + tid];
      if (nm){ nl += 1.f - dot; if (b == 0) nc += 1.f; }
      if (fm){ fl += fmaxf(dot - 0.2f, 0.f); if (b == 0) fc += 1.f; }
    }
  }
  nl = wred_sum(nl); fl = wred_sum(fl); nc = wred_sum(nc); fc = wred_sum(fc);
  int w = tid >> 6, lane = tid & 63;
  if (lane == 0){ wsum[w][0] = nl; wsum[w][1] = fl; wsum[w][2] = nc; wsum[w][3] = fc; }
  __syncthreads();
  if (tid == 0){
    float a0 = 0, a1 = 0, a2 = 0, a3 = 0;
    for (int i = 0; i < 8; i++){ a0 += wsum[i][0]; a1 += wsum[i][1]; a2 += wsum[i][2]; a3 += wsum[i][3]; }
    atomicAdd(&accum[0], a0); atomicAdd(&accum[1], a1);
    if (b == 0){ atomicAdd(&accum[2], a2); atomicAdd(&accum[3], a3); }
  }
}

__global__ void k_final(const float* __restrict__ accum, float* __restrict__ outp){
  if (threadIdx.x == 0){
    float loss = accum[0] / fmaxf(accum[2], 1.f) + accum[1] / fmaxf(accum[3], 1.f);
    outp[REGS * DR_] = loss;
  }
}

extern "C" void kernel_launch(void* const* d_in, const int* in_sizes, int n_in,
                              void* d_out, int out_size, void* d_ws, size_t ws_size,
                              hipStream_t stream){
  const float* pt    = (const float*)d_in[0];
  const int*   pmask = (const int*)d_in[1];
  const int*   nearm = (const int*)d_in[2];
  const int*   farm  = (const int*)d_in[3];
  const float* lp    = (const float*)d_in[4];
  const float* glnw  = (const float*)d_in[5];
  const float* glnb  = (const float*)d_in[6];
  const float* gw1   = (const float*)d_in[7];
  const float* gb1   = (const float*)d_in[8];
  const float* gw2   = (const float*)d_in[9];
  const float* pln1w = (const float*)d_in[11];
  const float* pln1b = (const float*)d_in[12];
  const float* pw1   = (const float*)d_in[13];
  const float* pb1   = (const float*)d_in[14];
  const float* pw2   = (const float*)d_in[15];
  const float* pb2   = (const float*)d_in[16];
  const float* pln2w = (const float*)d_in[17];
  const float* pln2b = (const float*)d_in[18];
  const float* inpw  = (const float*)d_in[19];
  const float* xpw   = (const float*)d_in[20];
  const float* dtw   = (const float*)d_in[21];
  const float* dtb   = (const float*)d_in[22];
  const float* alog  = (const float*)d_in[23];
  const float* dpar  = (const float*)d_in[24];
  const float* opw   = (const float*)d_in[25];
  const float* slnw  = (const float*)d_in[26];
  const float* slnb  = (const float*)d_in[27];

  char* ws = (char*)d_ws;
  size_t off = 0;
  auto alloc = [&](size_t bytes){ size_t o = off; off += (bytes + 255) & ~(size_t)255; return o; };
  ushort_t* W1pT  = (ushort_t*)(ws + alloc((size_t)DR_ * DP_ * 2));
  float* s1     = (float*)(ws + alloc(DR_ * 4));
  float* b1p    = (float*)(ws + alloc(DR_ * 4));
  ushort_t* wblob = (ushort_t*)(ws + alloc((size_t)NW_TOT * 2));
  ushort_t* xb  = (ushort_t*)(ws + alloc((size_t)MROWS * DP_ * 2));
  float* mu     = (float*)(ws + alloc((size_t)MROWS * 4));
  float* rsg    = (float*)(ws + alloc((size_t)MROWS * 4));
  float* pooled = (float*)(ws + alloc((size_t)REGS * DP_ * 4));
  float* region = (float*)(ws + alloc((size_t)REGS * DR_ * 4));
  float* uT     = (float*)(ws + alloc((size_t)REGS * DR_ * 4));
  float* zT     = (float*)(ws + alloc((size_t)REGS * DR_ * 4));
  float* deltaT = (float*)(ws + alloc((size_t)REGS * DR_ * 4));
  float* BmT    = (float*)(ws + alloc((size_t)REGS * N_ * 4));
  float* CmT    = (float*)(ws + alloc((size_t)REGS * N_ * 4));
  float* ys     = (float*)(ws + alloc((size_t)REGS * DR_ * 4));
  float* rt     = (float*)(ws + alloc((size_t)REGS * DR_ * 4));
  float* accum  = (float*)(ws + alloc(4 * 4));

  float* outp = (float*)d_out;

  k_prep<<<dim3(8), dim3(512), 0, stream>>>(gw1, glnw, glnb, gb1, W1pT, s1, b1p, accum);
  k_cast<<<dim3((NW_TOT / 4 + 511) / 512), dim3(512), 0, stream>>>(pw1, pw2, inpw, xpw, dtw, wblob);
  k_xform<<<dim3(MROWS / 8), dim3(512), 0, stream>>>(pt, lp, xb, mu, rsg);
  k_gate_pool<<<dim3(REGS), dim3(512), 0, stream>>>(xb, W1pT, mu, rsg, s1, b1p, gw2, pmask, pooled);
  k_region<<<dim3(REGS / 2), dim3(512), 0, stream>>>(pooled, pln1w, pln1b, wblob, pb1, pb2, pln2w, pln2b,
                                                     dtb, region, uT, zT, deltaT, BmT, CmT);
  k_scan<<<dim3(B_ * DR_), dim3(256), 0, stream>>>(deltaT, uT, zT, BmT, CmT, alog, dpar, ys);
  k_out<<<dim3(REGS / 4), dim3(512), 0, stream>>>(ys, opw, region, slnw, slnb, outp, rt);
  k_loss<<<dim3(REGS / 4), dim3(512), 0, stream>>>(rt, nearm, farm, accum);
  k_final<<<dim3(1), dim3(64), 0, stream>>>(accum, outp);
}